// Round 5
// baseline (133.851 us; speedup 1.0000x reference)
//
#include <hip/hip_runtime.h>
#include <hip/hip_fp16.h>
#include <math.h>

constexpr int PAD = 0;
constexpr int Lc = 128;   // sequence length
constexpr int Dc = 128;   // embedding dim
constexpr int NSLICE = 8; // one vocab slice per XCD
constexpr float MIN_NORM = 1e-15f;
constexpr float CLAMP_ABS_EPS = 1e-10f;
constexpr float ATANH_EPS = 1e-7f;

__device__ __forceinline__ float red64(float v) {
    v += __shfl_xor(v, 32);
    v += __shfl_xor(v, 16);
    v += __shfl_xor(v, 8);
    v += __shfl_xor(v, 4);
    v += __shfl_xor(v, 2);
    v += __shfl_xor(v, 1);
    return v;
}

// ---- pass 1: lam[v] = 2/clip(1-||emb[v]||^2) AND fp16 copy of the table ----
__global__ __launch_bounds__(256) void prep_kernel(
        const float* __restrict__ emb,
        __half* __restrict__ emb16,
        float* __restrict__ lam, int V) {
    const int row  = blockIdx.x * 4 + (threadIdx.x >> 6);
    const int lane = threadIdx.x & 63;
    if (row >= V) return;
    const float2 z = *reinterpret_cast<const float2*>(emb + (size_t)row * Dc + lane * 2);
    const float p = red64(z.x * z.x + z.y * z.y);
    if (lane == 0) lam[row] = 2.0f / fmaxf(1.0f - p, MIN_NORM);
    *reinterpret_cast<__half2*>(emb16 + (size_t)row * Dc + lane * 2) =
        __floats2half2_rn(z.x, z.y);
}

// ---- pass 2: per-(row,slice) partial sums; blocks claim work on their own XCD's slice ----
__global__ __launch_bounds__(256) void partial_kernel(
        const int* __restrict__ padded,
        const __half* __restrict__ emb16,
        const float* __restrict__ lam,
        uint2* __restrict__ pnum,      // [Bn*8][32] packed half2x2 (128 dims)
        float2* __restrict__ pmeta,    // [Bn*8] (sum_lam, cnt)
        int* __restrict__ counters,    // [8] work-claim counters (pre-zeroed)
        int Bn, int V) {
    const int V8   = (V + NSLICE - 1) / NSLICE;
    const int tid  = threadIdx.x;
    const int w    = tid >> 6;
    const int lane = tid & 63;
    const int half = lane >> 5;
    const int l32  = lane & 31;

    __shared__ int   s_r0, s_sl;
    __shared__ int   sl_idx[4][Lc];
    __shared__ float sl_lam[4][Lc];

    if (tid == 0) {
        unsigned xcc;
        asm volatile("s_getreg_b32 %0, hwreg(HW_REG_XCC_ID)" : "=s"(xcc));
        xcc &= (NSLICE - 1);
        int fr0 = -1, fs = 0;
        for (int t = 0; t < NSLICE; ++t) {           // try own slice, then steal
            const int s  = ((int)xcc + t) & (NSLICE - 1);
            const int r0 = atomicAdd(&counters[s], 8);
            if (r0 < Bn) { fr0 = r0; fs = s; break; }
        }
        s_r0 = fr0; s_sl = fs;
    }
    __syncthreads();
    const int r0 = s_r0, sl = s_sl;
    if (r0 < 0) return;                              // block-uniform (cannot happen when grid==chunks)
    const int sLo = sl * V8;

    #pragma unroll
    for (int rr = 0; rr < 2; ++rr) {
        const int  row   = r0 + w * 2 + rr;          // waves cover rows r0..r0+7
        const bool rowok = row < Bn;
        const int* prow  = padded + (size_t)row * Lc;
        const int  i0 = rowok ? prow[lane]      : PAD;
        const int  i1 = rowok ? prow[64 + lane] : PAD;
        const bool p0 = (i0 != PAD) && ((unsigned)(i0 - sLo) < (unsigned)V8);
        const bool p1 = (i1 != PAD) && ((unsigned)(i1 - sLo) < (unsigned)V8);
        const float la0 = p0 ? lam[i0] : 0.f;
        const float la1 = p1 ? lam[i1] : 0.f;
        const unsigned long long b0 = __ballot(p0);
        const unsigned long long b1 = __ballot(p1);
        const int c0  = __popcll(b0);
        const int cnt = c0 + __popcll(b1);
        const float lsum = red64(la0 + la1);
        const unsigned long long lmask = (1ull << lane) - 1ull;
        if (p0) { const int q = __popcll(b0 & lmask);      sl_idx[w][q] = i0; sl_lam[w][q] = la0; }
        if (p1) { const int q = c0 + __popcll(b1 & lmask); sl_idx[w][q] = i1; sl_lam[w][q] = la1; }
        __syncthreads();

        float4 acc = make_float4(0.f, 0.f, 0.f, 0.f);
        for (int k = half; k < cnt; k += 2) {        // compacted in-slice tokens only
            const int   idx = sl_idx[w][k];
            const float wl  = sl_lam[w][k];
            const float2 raw = *reinterpret_cast<const float2*>(
                emb16 + (size_t)idx * Dc + l32 * 4);
            const float2 f0 = __half22float2(*reinterpret_cast<const __half2*>(&raw.x));
            const float2 f1 = __half22float2(*reinterpret_cast<const __half2*>(&raw.y));
            acc.x = fmaf(wl, f0.x, acc.x);
            acc.y = fmaf(wl, f0.y, acc.y);
            acc.z = fmaf(wl, f1.x, acc.z);
            acc.w = fmaf(wl, f1.y, acc.w);
        }
        acc.x += __shfl_xor(acc.x, 32);
        acc.y += __shfl_xor(acc.y, 32);
        acc.z += __shfl_xor(acc.z, 32);
        acc.w += __shfl_xor(acc.w, 32);
        if (rowok && lane < 32) {
            const __half2 h0 = __floats2half2_rn(acc.x, acc.y);
            const __half2 h1 = __floats2half2_rn(acc.z, acc.w);
            uint2 u;
            u.x = *reinterpret_cast<const unsigned*>(&h0);
            u.y = *reinterpret_cast<const unsigned*>(&h1);
            pnum[((size_t)row * NSLICE + sl) * 32 + l32] = u;
        }
        if (rowok && lane == 0)
            pmeta[(size_t)row * NSLICE + sl] = make_float2(lsum, (float)cnt);
        __syncthreads();
    }
}

// ---- pass 3: sum 8 partials per row, norm chain, write 4 replicated chunks ----
__global__ __launch_bounds__(64) void final_kernel(
        const uint2* __restrict__ pnum,
        const float2* __restrict__ pmeta,
        float* __restrict__ out, int Bn) {
    const int row  = blockIdx.x;
    const int lane = threadIdx.x;      // 0..63
    const int h    = lane >> 5;
    const int p    = lane & 31;

    float4 v = make_float4(0.f, 0.f, 0.f, 0.f);
    #pragma unroll
    for (int j = 0; j < 4; ++j) {
        const int s = h * 4 + j;
        const uint2 u = pnum[((size_t)row * NSLICE + s) * 32 + p];
        const float2 f0 = __half22float2(*reinterpret_cast<const __half2*>(&u.x));
        const float2 f1 = __half22float2(*reinterpret_cast<const __half2*>(&u.y));
        v.x += f0.x; v.y += f0.y; v.z += f1.x; v.w += f1.y;
    }
    v.x += __shfl_xor(v.x, 32);
    v.y += __shfl_xor(v.y, 32);
    v.z += __shfl_xor(v.z, 32);
    v.w += __shfl_xor(v.w, 32);

    float2 m = make_float2(0.f, 0.f);
    if (lane < NSLICE) m = pmeta[(size_t)row * NSLICE + lane];
    const float slam = red64(m.x);
    const float cntf = red64(m.y);

    float* orow = out + (size_t)row * (4 * Dc);
    if (cntf == 0.f) {
        if (lane < 32) {
            const float4 z4 = make_float4(0.f, 0.f, 0.f, 0.f);
            #pragma unroll
            for (int sc = 0; sc < 4; ++sc)
                *reinterpret_cast<float4*>(orow + sc * Dc + 4 * p) = z4;
        }
        return;
    }

    const float rc    = 1.0f / cntf;
    const float dn    = (slam - cntf) * rc;                     // mean(lam-1)
    const float denom = ((dn >= 0.f) ? 1.0f : -1.0f) * fmaxf(fabsf(dn), CLAMP_ABS_EPS);
    const float s1    = rc / denom;
    const float4 tm = make_float4(v.x * s1, v.y * s1, v.z * s1, v.w * s1);

    const float p2 = (lane < 32) ? (tm.x*tm.x + tm.y*tm.y + tm.z*tm.z + tm.w*tm.w) : 0.f;
    const float n2 = fmaxf(sqrtf(red64(p2)), MIN_NORM);
    const float xc = fminf(n2, 1.0f - ATANH_EPS);
    const float th = xc / (1.0f + sqrtf(fmaxf(1.0f - xc * xc, 0.f)));  // tanh(0.5*artanh)
    const float k1 = th / n2;
    const float4 mid = make_float4(tm.x * k1, tm.y * k1, tm.z * k1, tm.w * k1);

    const float q2 = (lane < 32) ? (mid.x*mid.x + mid.y*mid.y + mid.z*mid.z + mid.w*mid.w) : 0.f;
    const float nm  = fmaxf(sqrtf(red64(q2)), MIN_NORM);
    const float xc2 = fminf(nm, 1.0f - ATANH_EPS);
    const float f   = 0.5f * logf((1.0f + xc2) / (1.0f - xc2));        // artanh
    const float k2  = f / nm;

    if (lane < 32) {
        const float4 o = make_float4(mid.x * k2, mid.y * k2, mid.z * k2, mid.w * k2);
        #pragma unroll
        for (int sc = 0; sc < 4; ++sc)
            *reinterpret_cast<float4*>(orow + sc * Dc + 4 * p) = o;
    }
}

// ---- fallback: round-4 fp16 single main kernel ----
__global__ __launch_bounds__(256) void hyper_enc_kernel(
        const int* __restrict__ padded,
        const __half* __restrict__ emb16,
        const float* __restrict__ lam,
        float* __restrict__ out) {
    const int b    = blockIdx.x;
    const int tid  = threadIdx.x;
    const int wave = tid >> 6;
    const int lane = tid & 63;
    const int half = lane >> 5;
    const int l32  = lane & 31;

    __shared__ int   sidx[Lc];
    __shared__ float slam[Lc];
    __shared__ float s_num[8][Dc];
    __shared__ int   s_cnt;
    __shared__ float s_den[2];
    __shared__ float s_red[4];

    int   myidx = 0;
    float mylam = 0.f;
    if (tid < Lc) {
        myidx = padded[(size_t)b * Lc + tid];
        sidx[tid] = myidx;
        mylam = (myidx != PAD) ? lam[myidx] : 0.0f;
        slam[tid] = mylam;
    }
    if (tid == 0) s_cnt = 0;
    __syncthreads();
    if (tid < Lc) {
        unsigned long long bal = __ballot(myidx != PAD);
        if (lane == 0) atomicAdd(&s_cnt, (int)__popcll(bal));
        float sl = red64(mylam);
        if (lane == 0) s_den[wave] = sl;
    }

    float4 snum = make_float4(0.f, 0.f, 0.f, 0.f);
    const int lbase = wave * 32 + half;
    __syncthreads();
    #pragma unroll
    for (int j = 0; j < 16; ++j) {
        const int   l   = lbase + 2 * j;
        const int   idx = sidx[l];
        const float wl  = slam[l];
        const float2 raw = *reinterpret_cast<const float2*>(
            emb16 + (size_t)idx * Dc + l32 * 4);
        const float2 f0 = __half22float2(*reinterpret_cast<const __half2*>(&raw.x));
        const float2 f1 = __half22float2(*reinterpret_cast<const __half2*>(&raw.y));
        snum.x = fmaf(wl, f0.x, snum.x);
        snum.y = fmaf(wl, f0.y, snum.y);
        snum.z = fmaf(wl, f1.x, snum.z);
        snum.w = fmaf(wl, f1.y, snum.w);
    }
    const int g = wave * 2 + half;
    *reinterpret_cast<float4*>(&s_num[g][l32 * 4]) = snum;
    __syncthreads();

    const int cnt = s_cnt;
    if (cnt == 0) {
        for (int i = tid; i < 4 * Dc; i += 256)
            out[(size_t)b * (4 * Dc) + i] = 0.f;
        return;
    }
    const float Sd = (s_den[0] + s_den[1]) - (float)cnt;

    float nom = 0.f;
    if (tid < Dc) {
        #pragma unroll
        for (int gg = 0; gg < 8; ++gg) nom += s_num[gg][tid];
    }
    float tm = 0.f;
    if (tid < Dc) {
        const float rc    = 1.0f / (float)cnt;
        const float dn    = Sd * rc;
        const float denom = ((dn >= 0.f) ? 1.0f : -1.0f) * fmaxf(fabsf(dn), CLAMP_ABS_EPS);
        tm = (nom * rc) / denom;
    }
    float p2 = red64(tm * tm);
    if (lane == 0) s_red[wave] = p2;
    __syncthreads();
    const float n2 = fmaxf(sqrtf(s_red[0] + s_red[1]), MIN_NORM);
    const float xc = fminf(n2, 1.0f - ATANH_EPS);
    const float t_half = xc / (1.0f + sqrtf(fmaxf(1.0f - xc * xc, 0.f)));
    const float mid = tm * (t_half / n2);
    __syncthreads();
    float q2 = red64(mid * mid);
    if (lane == 0) s_red[wave] = q2;
    __syncthreads();
    const float nm  = fmaxf(sqrtf(s_red[0] + s_red[1]), MIN_NORM);
    const float xc2 = fminf(nm, 1.0f - ATANH_EPS);
    const float f   = 0.5f * logf((1.0f + xc2) / (1.0f - xc2));
    if (tid < Dc) {
        const float o = mid * (f / nm);
        float* orow = out + (size_t)b * (4 * Dc);
        orow[0 * Dc + tid] = o;
        orow[1 * Dc + tid] = o;
        orow[2 * Dc + tid] = o;
        orow[3 * Dc + tid] = o;
    }
}

extern "C" void kernel_launch(void* const* d_in, const int* in_sizes, int n_in,
                              void* d_out, int out_size, void* d_ws, size_t ws_size,
                              hipStream_t stream) {
    const int*   padded = (const int*)d_in[0];
    const float* emb    = (const float*)d_in[1];
    float*       out    = (float*)d_out;
    const int Bn = in_sizes[0] / Lc;             // 8192
    const int V  = in_sizes[1] / Dc;             // 50000

    const size_t emb16_b = (size_t)V * Dc * sizeof(__half);        // 12.8 MB
    const size_t lam_b   = (size_t)V * sizeof(float);              // 200 KB
    const size_t pnum_b  = (size_t)Bn * NSLICE * 32 * sizeof(uint2);   // 16.8 MB
    const size_t pmeta_b = (size_t)Bn * NSLICE * sizeof(float2);   // 524 KB
    const size_t cnt_b   = 256;                                    // counters (padded)
    const size_t need    = emb16_b + lam_b + pnum_b + pmeta_b + cnt_b;

    if (ws_size >= need) {
        char* p = (char*)d_ws;
        __half* emb16    = (__half*)p;                 p += emb16_b;
        float*  lam      = (float*)p;                  p += lam_b;
        uint2*  pnum     = (uint2*)p;                  p += pnum_b;
        float2* pmeta    = (float2*)p;                 p += pmeta_b;
        int*    counters = (int*)p;
        prep_kernel<<<(V + 3) / 4, 256, 0, stream>>>(emb, emb16, lam, V);
        hipMemsetAsync(counters, 0, NSLICE * sizeof(int), stream);
        const int nchunks = NSLICE * ((Bn + 7) / 8);
        partial_kernel<<<nchunks, 256, 0, stream>>>(padded, emb16, lam,
                                                    pnum, pmeta, counters, Bn, V);
        final_kernel<<<Bn, 64, 0, stream>>>(pnum, pmeta, out, Bn);
    } else if (ws_size >= emb16_b + lam_b) {
        __half* emb16 = (__half*)d_ws;
        float*  lam   = (float*)((char*)d_ws + emb16_b);
        prep_kernel<<<(V + 3) / 4, 256, 0, stream>>>(emb, emb16, lam, V);
        hyper_enc_kernel<<<Bn, 256, 0, stream>>>(padded, emb16, lam, out);
    }
}

// Round 7
// 59.212 us; speedup vs baseline: 2.2605x; 2.2605x over previous
//
#include <hip/hip_runtime.h>
#include <hip/hip_fp16.h>
#include <math.h>

constexpr int PAD = 0;
constexpr int Lc = 128;   // sequence length
constexpr int Dc = 128;   // embedding dim
constexpr int NSLICE = 8; // one vocab slice per XCD
constexpr float MIN_NORM = 1e-15f;
constexpr float CLAMP_ABS_EPS = 1e-10f;
constexpr float ATANH_EPS = 1e-7f;

__device__ __forceinline__ float red64(float v) {
    v += __shfl_xor(v, 32);
    v += __shfl_xor(v, 16);
    v += __shfl_xor(v, 8);
    v += __shfl_xor(v, 4);
    v += __shfl_xor(v, 2);
    v += __shfl_xor(v, 1);
    return v;
}

// ---- pass 1: lam[v] = 2/clip(1-||emb[v]||^2) AND fp16 copy of the table ----
__global__ __launch_bounds__(256) void prep_kernel(
        const float* __restrict__ emb,
        __half* __restrict__ emb16,
        float* __restrict__ lam, int V) {
    const int row  = blockIdx.x * 4 + (threadIdx.x >> 6);
    const int lane = threadIdx.x & 63;
    if (row >= V) return;
    const float2 z = *reinterpret_cast<const float2*>(emb + (size_t)row * Dc + lane * 2);
    const float p = red64(z.x * z.x + z.y * z.y);
    if (lane == 0) lam[row] = 2.0f / fmaxf(1.0f - p, MIN_NORM);
    *reinterpret_cast<__half2*>(emb16 + (size_t)row * Dc + lane * 2) =
        __floats2half2_rn(z.x, z.y);
}

// ---- pass 2: per-(row,slice) partials; slice = blockIdx%8 (round-robin XCD
//      mapping gives L2 locality; correctness independent of the mapping) ----
__global__ __launch_bounds__(256) void partial_kernel(
        const int* __restrict__ padded,
        const __half* __restrict__ emb16,
        const float* __restrict__ lam,
        uint2* __restrict__ pnum,      // [Bn*8][32] packed half2x2 (128 dims)
        float2* __restrict__ pmeta,    // [Bn*8] (sum_lam_slice, cnt_slice)
        int Bn, int V) {
    const int V8   = (V + NSLICE - 1) / NSLICE;
    const int g    = blockIdx.x;
    const int sl   = g & (NSLICE - 1);
    const int r0   = (g >> 3) * 8;
    const int tid  = threadIdx.x;
    const int w    = tid >> 6;
    const int lane = tid & 63;
    const int half = lane >> 5;
    const int l32  = lane & 31;
    const int sLo  = sl * V8;

    __shared__ int   sl_idx[4][Lc];
    __shared__ float sl_lam[4][Lc];

    #pragma unroll
    for (int rr = 0; rr < 2; ++rr) {
        const int  row   = r0 + w * 2 + rr;          // waves cover rows r0..r0+7
        const bool rowok = row < Bn;
        const int* prow  = padded + (size_t)row * Lc;
        const int  i0 = rowok ? prow[lane]      : PAD;
        const int  i1 = rowok ? prow[64 + lane] : PAD;
        const bool p0 = (i0 != PAD) && ((unsigned)(i0 - sLo) < (unsigned)V8);
        const bool p1 = (i1 != PAD) && ((unsigned)(i1 - sLo) < (unsigned)V8);
        const float la0 = p0 ? lam[i0] : 0.f;
        const float la1 = p1 ? lam[i1] : 0.f;
        const unsigned long long b0 = __ballot(p0);
        const unsigned long long b1 = __ballot(p1);
        const int c0  = __popcll(b0);
        const int cnt = c0 + __popcll(b1);
        const float lsum = red64(la0 + la1);
        const unsigned long long lmask = (1ull << lane) - 1ull;
        // per-wave LDS compaction: no block barrier needed
        if (p0) { const int q = __popcll(b0 & lmask);      sl_idx[w][q] = i0; sl_lam[w][q] = la0; }
        if (p1) { const int q = c0 + __popcll(b1 & lmask); sl_idx[w][q] = i1; sl_lam[w][q] = la1; }

        float4 acc = make_float4(0.f, 0.f, 0.f, 0.f);
        for (int k = half; k < cnt; k += 2) {        // compacted in-slice tokens only
            const int   idx = sl_idx[w][k];
            const float wl  = sl_lam[w][k];
            const float2 raw = *reinterpret_cast<const float2*>(
                emb16 + (size_t)idx * Dc + l32 * 4);
            const float2 f0 = __half22float2(*reinterpret_cast<const __half2*>(&raw.x));
            const float2 f1 = __half22float2(*reinterpret_cast<const __half2*>(&raw.y));
            acc.x = fmaf(wl, f0.x, acc.x);
            acc.y = fmaf(wl, f0.y, acc.y);
            acc.z = fmaf(wl, f1.x, acc.z);
            acc.w = fmaf(wl, f1.y, acc.w);
        }
        acc.x += __shfl_xor(acc.x, 32);
        acc.y += __shfl_xor(acc.y, 32);
        acc.z += __shfl_xor(acc.z, 32);
        acc.w += __shfl_xor(acc.w, 32);
        if (rowok && lane < 32) {
            const __half2 h0 = __floats2half2_rn(acc.x, acc.y);
            const __half2 h1 = __floats2half2_rn(acc.z, acc.w);
            uint2 u;
            u.x = *reinterpret_cast<const unsigned*>(&h0);
            u.y = *reinterpret_cast<const unsigned*>(&h1);
            pnum[((size_t)row * NSLICE + sl) * 32 + l32] = u;
        }
        if (rowok && lane == 0)
            pmeta[(size_t)row * NSLICE + sl] = make_float2(lsum, (float)cnt);
    }
}

// ---- pass 3: sum 8 partials per row, norm chain, write 4 replicated chunks ----
__global__ __launch_bounds__(64) void final_kernel(
        const uint2* __restrict__ pnum,
        const float2* __restrict__ pmeta,
        float* __restrict__ out, int Bn) {
    const int row  = blockIdx.x;
    const int lane = threadIdx.x;      // 0..63
    const int h    = lane >> 5;
    const int p    = lane & 31;

    float4 v = make_float4(0.f, 0.f, 0.f, 0.f);
    #pragma unroll
    for (int j = 0; j < 4; ++j) {
        const int s = h * 4 + j;
        const uint2 u = pnum[((size_t)row * NSLICE + s) * 32 + p];
        const float2 f0 = __half22float2(*reinterpret_cast<const __half2*>(&u.x));
        const float2 f1 = __half22float2(*reinterpret_cast<const __half2*>(&u.y));
        v.x += f0.x; v.y += f0.y; v.z += f1.x; v.w += f1.y;
    }
    v.x += __shfl_xor(v.x, 32);
    v.y += __shfl_xor(v.y, 32);
    v.z += __shfl_xor(v.z, 32);
    v.w += __shfl_xor(v.w, 32);

    float2 m = make_float2(0.f, 0.f);
    if (lane < NSLICE) m = pmeta[(size_t)row * NSLICE + lane];
    const float slam = red64(m.x);
    const float cntf = red64(m.y);

    float* orow = out + (size_t)row * (4 * Dc);
    if (cntf == 0.f) {
        if (lane < 32) {
            const float4 z4 = make_float4(0.f, 0.f, 0.f, 0.f);
            #pragma unroll
            for (int sc = 0; sc < 4; ++sc)
                *reinterpret_cast<float4*>(orow + sc * Dc + 4 * p) = z4;
        }
        return;
    }

    const float rc    = 1.0f / cntf;
    const float dn    = (slam - cntf) * rc;                     // mean(lam-1)
    const float denom = ((dn >= 0.f) ? 1.0f : -1.0f) * fmaxf(fabsf(dn), CLAMP_ABS_EPS);
    const float s1    = rc / denom;
    const float4 tm = make_float4(v.x * s1, v.y * s1, v.z * s1, v.w * s1);

    const float p2 = (lane < 32) ? (tm.x*tm.x + tm.y*tm.y + tm.z*tm.z + tm.w*tm.w) : 0.f;
    const float n2 = fmaxf(sqrtf(red64(p2)), MIN_NORM);
    const float xc = fminf(n2, 1.0f - ATANH_EPS);
    const float th = xc / (1.0f + sqrtf(fmaxf(1.0f - xc * xc, 0.f)));  // tanh(0.5*artanh)
    const float k1 = th / n2;
    const float4 mid = make_float4(tm.x * k1, tm.y * k1, tm.z * k1, tm.w * k1);

    const float q2 = (lane < 32) ? (mid.x*mid.x + mid.y*mid.y + mid.z*mid.z + mid.w*mid.w) : 0.f;
    const float nm  = fmaxf(sqrtf(red64(q2)), MIN_NORM);
    const float xc2 = fminf(nm, 1.0f - ATANH_EPS);
    const float f   = 0.5f * logf((1.0f + xc2) / (1.0f - xc2));        // artanh
    const float k2  = f / nm;

    if (lane < 32) {
        const float4 o = make_float4(mid.x * k2, mid.y * k2, mid.z * k2, mid.w * k2);
        #pragma unroll
        for (int sc = 0; sc < 4; ++sc)
            *reinterpret_cast<float4*>(orow + sc * Dc + 4 * p) = o;
    }
}

// ---- fallback: round-4 fp16 single main kernel ----
__global__ __launch_bounds__(256) void hyper_enc_kernel(
        const int* __restrict__ padded,
        const __half* __restrict__ emb16,
        const float* __restrict__ lam,
        float* __restrict__ out) {
    const int b    = blockIdx.x;
    const int tid  = threadIdx.x;
    const int wave = tid >> 6;
    const int lane = tid & 63;
    const int half = lane >> 5;
    const int l32  = lane & 31;

    __shared__ int   sidx[Lc];
    __shared__ float slam[Lc];
    __shared__ float s_num[8][Dc];
    __shared__ int   s_cnt;
    __shared__ float s_den[2];
    __shared__ float s_red[4];

    int   myidx = 0;
    float mylam = 0.f;
    if (tid < Lc) {
        myidx = padded[(size_t)b * Lc + tid];
        sidx[tid] = myidx;
        mylam = (myidx != PAD) ? lam[myidx] : 0.0f;
        slam[tid] = mylam;
    }
    if (tid == 0) s_cnt = 0;
    __syncthreads();
    if (tid < Lc) {
        unsigned long long bal = __ballot(myidx != PAD);
        if (lane == 0) atomicAdd(&s_cnt, (int)__popcll(bal));
        float sl = red64(mylam);
        if (lane == 0) s_den[wave] = sl;
    }

    float4 snum = make_float4(0.f, 0.f, 0.f, 0.f);
    const int lbase = wave * 32 + half;
    __syncthreads();
    #pragma unroll
    for (int j = 0; j < 16; ++j) {
        const int   l   = lbase + 2 * j;
        const int   idx = sidx[l];
        const float wl  = slam[l];
        const float2 raw = *reinterpret_cast<const float2*>(
            emb16 + (size_t)idx * Dc + l32 * 4);
        const float2 f0 = __half22float2(*reinterpret_cast<const __half2*>(&raw.x));
        const float2 f1 = __half22float2(*reinterpret_cast<const __half2*>(&raw.y));
        snum.x = fmaf(wl, f0.x, snum.x);
        snum.y = fmaf(wl, f0.y, snum.y);
        snum.z = fmaf(wl, f1.x, snum.z);
        snum.w = fmaf(wl, f1.y, snum.w);
    }
    const int g = wave * 2 + half;
    *reinterpret_cast<float4*>(&s_num[g][l32 * 4]) = snum;
    __syncthreads();

    const int cnt = s_cnt;
    if (cnt == 0) {
        for (int i = tid; i < 4 * Dc; i += 256)
            out[(size_t)b * (4 * Dc) + i] = 0.f;
        return;
    }
    const float Sd = (s_den[0] + s_den[1]) - (float)cnt;

    float nom = 0.f;
    if (tid < Dc) {
        #pragma unroll
        for (int gg = 0; gg < 8; ++gg) nom += s_num[gg][tid];
    }
    float tm = 0.f;
    if (tid < Dc) {
        const float rc    = 1.0f / (float)cnt;
        const float dn    = Sd * rc;
        const float denom = ((dn >= 0.f) ? 1.0f : -1.0f) * fmaxf(fabsf(dn), CLAMP_ABS_EPS);
        tm = (nom * rc) / denom;
    }
    float p2 = red64(tm * tm);
    if (lane == 0) s_red[wave] = p2;
    __syncthreads();
    const float n2 = fmaxf(sqrtf(s_red[0] + s_red[1]), MIN_NORM);
    const float xc = fminf(n2, 1.0f - ATANH_EPS);
    const float t_half = xc / (1.0f + sqrtf(fmaxf(1.0f - xc * xc, 0.f)));
    const float mid = tm * (t_half / n2);
    __syncthreads();
    float q2 = red64(mid * mid);
    if (lane == 0) s_red[wave] = q2;
    __syncthreads();
    const float nm  = fmaxf(sqrtf(s_red[0] + s_red[1]), MIN_NORM);
    const float xc2 = fminf(nm, 1.0f - ATANH_EPS);
    const float f   = 0.5f * logf((1.0f + xc2) / (1.0f - xc2));
    if (tid < Dc) {
        const float o = mid * (f / nm);
        float* orow = out + (size_t)b * (4 * Dc);
        orow[0 * Dc + tid] = o;
        orow[1 * Dc + tid] = o;
        orow[2 * Dc + tid] = o;
        orow[3 * Dc + tid] = o;
    }
}

extern "C" void kernel_launch(void* const* d_in, const int* in_sizes, int n_in,
                              void* d_out, int out_size, void* d_ws, size_t ws_size,
                              hipStream_t stream) {
    const int*   padded = (const int*)d_in[0];
    const float* emb    = (const float*)d_in[1];
    float*       out    = (float*)d_out;
    const int Bn = in_sizes[0] / Lc;             // 8192
    const int V  = in_sizes[1] / Dc;             // 50000

    const size_t emb16_b = (size_t)V * Dc * sizeof(__half);            // 12.8 MB
    const size_t lam_b   = (size_t)V * sizeof(float);                  // 200 KB
    const size_t pnum_b  = (size_t)Bn * NSLICE * 32 * sizeof(uint2);   // 16.8 MB
    const size_t pmeta_b = (size_t)Bn * NSLICE * sizeof(float2);       // 524 KB
    const size_t need    = emb16_b + lam_b + pnum_b + pmeta_b;

    if (ws_size >= need) {
        char* p = (char*)d_ws;
        __half* emb16 = (__half*)p;   p += emb16_b;
        float*  lam   = (float*)p;    p += lam_b;
        uint2*  pnum  = (uint2*)p;    p += pnum_b;
        float2* pmeta = (float2*)p;
        prep_kernel<<<(V + 3) / 4, 256, 0, stream>>>(emb, emb16, lam, V);
        const int nblocks = NSLICE * ((Bn + 7) / 8);
        partial_kernel<<<nblocks, 256, 0, stream>>>(padded, emb16, lam,
                                                    pnum, pmeta, Bn, V);
        final_kernel<<<Bn, 64, 0, stream>>>(pnum, pmeta, out, Bn);
    } else if (ws_size >= emb16_b + lam_b) {
        __half* emb16 = (__half*)d_ws;
        float*  lam   = (float*)((char*)d_ws + emb16_b);
        prep_kernel<<<(V + 3) / 4, 256, 0, stream>>>(emb, emb16, lam, V);
        hyper_enc_kernel<<<Bn, 256, 0, stream>>>(padded, emb16, lam, out);
    }
}

// Round 8
// 56.920 us; speedup vs baseline: 2.3516x; 1.0403x over previous
//
#include <hip/hip_runtime.h>
#include <hip/hip_fp16.h>
#include <math.h>

constexpr int PAD = 0;
constexpr int Lc = 128;   // sequence length
constexpr int Dc = 128;   // embedding dim
constexpr int NSLICE = 4; // vocab slices (XCD k owns slice k%4 under round-robin)
constexpr float MIN_NORM = 1e-15f;
constexpr float CLAMP_ABS_EPS = 1e-10f;
constexpr float ATANH_EPS = 1e-7f;

__device__ __forceinline__ float red64(float v) {
    v += __shfl_xor(v, 32);
    v += __shfl_xor(v, 16);
    v += __shfl_xor(v, 8);
    v += __shfl_xor(v, 4);
    v += __shfl_xor(v, 2);
    v += __shfl_xor(v, 1);
    return v;
}

// ---- pass 1: lam[v] and w16[v] = fp16(lam[v] * z[v]) (lam folded into table) ----
__global__ __launch_bounds__(256) void prep_kernel(
        const float* __restrict__ emb,
        __half* __restrict__ w16,
        float* __restrict__ lam, int V) {
    const int row  = blockIdx.x * 4 + (threadIdx.x >> 6);
    const int lane = threadIdx.x & 63;
    if (row >= V) return;
    const float2 z = *reinterpret_cast<const float2*>(emb + (size_t)row * Dc + lane * 2);
    const float p = red64(z.x * z.x + z.y * z.y);
    const float lamv = 2.0f / fmaxf(1.0f - p, MIN_NORM);
    if (lane == 0) lam[row] = lamv;
    *reinterpret_cast<__half2*>(w16 + (size_t)row * Dc + lane * 2) =
        __floats2half2_rn(lamv * z.x, lamv * z.y);
}

// ---- pass 2: per-row bucket: slice-sorted compact token lists + row meta ----
__global__ __launch_bounds__(256) void bucket_kernel(
        const int* __restrict__ padded,
        const float* __restrict__ lam,
        unsigned short* __restrict__ cidx,   // [Bn][128] slice-sorted token ids
        unsigned short* __restrict__ offs,   // [Bn][4] slice start offsets
        float* __restrict__ slamArr,         // [Bn]
        int* __restrict__ cntArr,            // [Bn]
        int Bn, int V4) {
    const int row  = blockIdx.x * 4 + (threadIdx.x >> 6);
    const int lane = threadIdx.x & 63;
    if (row >= Bn) return;

    const int i0 = padded[(size_t)row * Lc + lane];
    const int i1 = padded[(size_t)row * Lc + 64 + lane];
    const bool p0 = (i0 != PAD);
    const bool p1 = (i1 != PAD);
    const float la0 = p0 ? lam[i0] : 0.f;
    const float la1 = p1 ? lam[i1] : 0.f;
    const float slam = red64(la0 + la1);
    // exact slice via compares (float-reciprocal is unsafe at boundaries)
    const int s0 = (i0 >= V4) + (i0 >= 2 * V4) + (i0 >= 3 * V4);
    const int s1 = (i1 >= V4) + (i1 >= 2 * V4) + (i1 >= 3 * V4);
    const unsigned long long lmask = (1ull << lane) - 1ull;

    int running = 0;
    #pragma unroll
    for (int s = 0; s < NSLICE; ++s) {
        const unsigned long long m0 = __ballot(p0 && (s0 == s));
        const unsigned long long m1 = __ballot(p1 && (s1 == s));
        const int c0 = __popcll(m0);
        if (lane == 0) offs[(size_t)row * NSLICE + s] = (unsigned short)running;
        if (p0 && (s0 == s))
            cidx[(size_t)row * Lc + running + __popcll(m0 & lmask)] = (unsigned short)i0;
        if (p1 && (s1 == s))
            cidx[(size_t)row * Lc + running + c0 + __popcll(m1 & lmask)] = (unsigned short)i1;
        running += c0 + __popcll(m1);
    }
    if (lane == 0) { slamArr[row] = slam; cntArr[row] = running; }
}

// ---- pass 3: slice-local gather-add (lean hot loop, fp16 pk adds) ----
__global__ __launch_bounds__(256) void partial_kernel(
        const unsigned short* __restrict__ cidx,
        const unsigned short* __restrict__ offs,
        const int* __restrict__ cntArr,
        const __half* __restrict__ w16,
        uint2* __restrict__ pnum,      // [Bn*4][32] packed half2x2 (128 dims)
        int Bn) {
    const int sl   = blockIdx.x & (NSLICE - 1);   // round-robin -> same XCD per slice
    const int r0   = (blockIdx.x >> 2) * 8;
    const int tid  = threadIdx.x;
    const int w    = tid >> 6;
    const int lane = tid & 63;
    const int half = lane >> 5;
    const int l32  = lane & 31;

    __shared__ int sidx[4][2][Lc];

    #pragma unroll
    for (int rr = 0; rr < 2; ++rr) {
        const int row = r0 + w * 2 + rr;
        if (row >= Bn) continue;
        const int off = offs[(size_t)row * NSLICE + sl];
        const int nxt = (sl < NSLICE - 1) ? (int)offs[(size_t)row * NSLICE + sl + 1]
                                          : cntArr[row];
        const int cnt = nxt - off;
        if (lane < cnt)
            sidx[w][rr][lane] = (int)cidx[(size_t)row * Lc + off + lane];
        if (cnt > 64 && lane < cnt - 64)
            sidx[w][rr][64 + lane] = (int)cidx[(size_t)row * Lc + off + 64 + lane];

        __half2 a0 = __floats2half2_rn(0.f, 0.f);
        __half2 a1 = a0;
        for (int k = half; k < cnt; k += 2) {
            const int idx = sidx[w][rr][k];
            const uint2 r = *reinterpret_cast<const uint2*>(
                w16 + ((size_t)idx << 7) + (l32 << 2));
            a0 = __hadd2(a0, *reinterpret_cast<const __half2*>(&r.x));
            a1 = __hadd2(a1, *reinterpret_cast<const __half2*>(&r.y));
        }
        // combine the two 32-lane halves (different tokens, same dims)
        unsigned u0 = *reinterpret_cast<unsigned*>(&a0);
        unsigned u1 = *reinterpret_cast<unsigned*>(&a1);
        const unsigned o0 = __shfl_xor(u0, 32);
        const unsigned o1 = __shfl_xor(u1, 32);
        a0 = __hadd2(a0, *reinterpret_cast<const __half2*>(&o0));
        a1 = __hadd2(a1, *reinterpret_cast<const __half2*>(&o1));
        if (lane < 32) {
            uint2 u;
            u.x = *reinterpret_cast<unsigned*>(&a0);
            u.y = *reinterpret_cast<unsigned*>(&a1);
            pnum[((size_t)row * NSLICE + sl) * 32 + l32] = u;
        }
    }
}

// ---- pass 4: sum 4 partials per row, norm chain, write 4 replicated chunks ----
__global__ __launch_bounds__(256) void final_kernel(
        const uint2* __restrict__ pnum,
        const float* __restrict__ slamArr,
        const int* __restrict__ cntArr,
        float* __restrict__ out, int Bn) {
    const int row  = blockIdx.x * 4 + (threadIdx.x >> 6);
    const int lane = threadIdx.x & 63;
    const int h    = lane >> 5;
    const int p    = lane & 31;
    if (row >= Bn) return;

    const int   cnt  = cntArr[row];
    float* orow = out + (size_t)row * (4 * Dc);
    if (cnt == 0) {
        if (lane < 32) {
            const float4 z4 = make_float4(0.f, 0.f, 0.f, 0.f);
            #pragma unroll
            for (int sc = 0; sc < 4; ++sc)
                *reinterpret_cast<float4*>(orow + sc * Dc + 4 * p) = z4;
        }
        return;
    }

    float4 v = make_float4(0.f, 0.f, 0.f, 0.f);
    #pragma unroll
    for (int j = 0; j < 2; ++j) {
        const int s = h * 2 + j;
        const uint2 u = pnum[((size_t)row * NSLICE + s) * 32 + p];
        const float2 f0 = __half22float2(*reinterpret_cast<const __half2*>(&u.x));
        const float2 f1 = __half22float2(*reinterpret_cast<const __half2*>(&u.y));
        v.x += f0.x; v.y += f0.y; v.z += f1.x; v.w += f1.y;
    }
    v.x += __shfl_xor(v.x, 32);
    v.y += __shfl_xor(v.y, 32);
    v.z += __shfl_xor(v.z, 32);
    v.w += __shfl_xor(v.w, 32);

    const float cntf = (float)cnt;
    const float rc    = 1.0f / cntf;
    const float dn    = (slamArr[row] - cntf) * rc;             // mean(lam-1)
    const float denom = ((dn >= 0.f) ? 1.0f : -1.0f) * fmaxf(fabsf(dn), CLAMP_ABS_EPS);
    const float s1    = rc / denom;
    const float4 tm = make_float4(v.x * s1, v.y * s1, v.z * s1, v.w * s1);

    const float p2 = (lane < 32) ? (tm.x*tm.x + tm.y*tm.y + tm.z*tm.z + tm.w*tm.w) : 0.f;
    const float n2 = fmaxf(sqrtf(red64(p2)), MIN_NORM);
    const float xc = fminf(n2, 1.0f - ATANH_EPS);
    const float th = xc / (1.0f + sqrtf(fmaxf(1.0f - xc * xc, 0.f)));  // tanh(0.5*artanh)
    const float k1 = th / n2;
    const float4 mid = make_float4(tm.x * k1, tm.y * k1, tm.z * k1, tm.w * k1);

    const float q2 = (lane < 32) ? (mid.x*mid.x + mid.y*mid.y + mid.z*mid.z + mid.w*mid.w) : 0.f;
    const float nm  = fmaxf(sqrtf(red64(q2)), MIN_NORM);
    const float xc2 = fminf(nm, 1.0f - ATANH_EPS);
    const float f   = 0.5f * logf((1.0f + xc2) / (1.0f - xc2));        // artanh
    const float k2  = f / nm;

    if (lane < 32) {
        const float4 o = make_float4(mid.x * k2, mid.y * k2, mid.z * k2, mid.w * k2);
        #pragma unroll
        for (int sc = 0; sc < 4; ++sc)
            *reinterpret_cast<float4*>(orow + sc * Dc + 4 * p) = o;
    }
}

// ---- fallback (small ws): single-kernel gather over w16 table ----
__global__ __launch_bounds__(256) void hyper_enc_kernel(
        const int* __restrict__ padded,
        const __half* __restrict__ w16,
        const float* __restrict__ lam,
        float* __restrict__ out) {
    const int b    = blockIdx.x;
    const int tid  = threadIdx.x;
    const int wave = tid >> 6;
    const int lane = tid & 63;
    const int half = lane >> 5;
    const int l32  = lane & 31;

    __shared__ int   sidx[Lc];
    __shared__ float s_num[8][Dc];
    __shared__ int   s_cnt;
    __shared__ float s_den[2];
    __shared__ float s_red[4];

    int   myidx = 0;
    float mylam = 0.f;
    if (tid < Lc) {
        myidx = padded[(size_t)b * Lc + tid];
        sidx[tid] = myidx;
        mylam = (myidx != PAD) ? lam[myidx] : 0.0f;
    }
    if (tid == 0) s_cnt = 0;
    __syncthreads();
    if (tid < Lc) {
        unsigned long long bal = __ballot(myidx != PAD);
        if (lane == 0) atomicAdd(&s_cnt, (int)__popcll(bal));
        float sl = red64(mylam);
        if (lane == 0) s_den[wave] = sl;
    }

    float4 snum = make_float4(0.f, 0.f, 0.f, 0.f);
    const int lbase = wave * 32 + half;
    __syncthreads();
    #pragma unroll
    for (int j = 0; j < 16; ++j) {
        const int idx = sidx[lbase + 2 * j];
        const uint2 r = *reinterpret_cast<const uint2*>(
            w16 + ((size_t)idx << 7) + (l32 << 2));
        const float2 f0 = __half22float2(*reinterpret_cast<const __half2*>(&r.x));
        const float2 f1 = __half22float2(*reinterpret_cast<const __half2*>(&r.y));
        snum.x += f0.x; snum.y += f0.y; snum.z += f1.x; snum.w += f1.y;
    }
    const int g = wave * 2 + half;
    *reinterpret_cast<float4*>(&s_num[g][l32 * 4]) = snum;
    __syncthreads();

    const int cnt = s_cnt;
    if (cnt == 0) {
        for (int i = tid; i < 4 * Dc; i += 256)
            out[(size_t)b * (4 * Dc) + i] = 0.f;
        return;
    }
    const float Sd = (s_den[0] + s_den[1]) - (float)cnt;

    float nom = 0.f;
    if (tid < Dc) {
        #pragma unroll
        for (int gg = 0; gg < 8; ++gg) nom += s_num[gg][tid];
    }
    float tm = 0.f;
    if (tid < Dc) {
        const float rc    = 1.0f / (float)cnt;
        const float dn    = Sd * rc;
        const float denom = ((dn >= 0.f) ? 1.0f : -1.0f) * fmaxf(fabsf(dn), CLAMP_ABS_EPS);
        tm = (nom * rc) / denom;
    }
    float p2 = red64(tm * tm);
    if (lane == 0) s_red[wave] = p2;
    __syncthreads();
    const float n2 = fmaxf(sqrtf(s_red[0] + s_red[1]), MIN_NORM);
    const float xc = fminf(n2, 1.0f - ATANH_EPS);
    const float t_half = xc / (1.0f + sqrtf(fmaxf(1.0f - xc * xc, 0.f)));
    const float mid = tm * (t_half / n2);
    __syncthreads();
    float q2 = red64(mid * mid);
    if (lane == 0) s_red[wave] = q2;
    __syncthreads();
    const float nm  = fmaxf(sqrtf(s_red[0] + s_red[1]), MIN_NORM);
    const float xc2 = fminf(nm, 1.0f - ATANH_EPS);
    const float f   = 0.5f * logf((1.0f + xc2) / (1.0f - xc2));
    if (tid < Dc) {
        const float o = mid * (f / nm);
        float* orow = out + (size_t)b * (4 * Dc);
        orow[0 * Dc + tid] = o;
        orow[1 * Dc + tid] = o;
        orow[2 * Dc + tid] = o;
        orow[3 * Dc + tid] = o;
    }
}

static inline size_t align256(size_t x) { return (x + 255) & ~(size_t)255; }

extern "C" void kernel_launch(void* const* d_in, const int* in_sizes, int n_in,
                              void* d_out, int out_size, void* d_ws, size_t ws_size,
                              hipStream_t stream) {
    const int*   padded = (const int*)d_in[0];
    const float* emb    = (const float*)d_in[1];
    float*       out    = (float*)d_out;
    const int Bn = in_sizes[0] / Lc;             // 8192
    const int V  = in_sizes[1] / Dc;             // 50000
    const int V4 = (V + NSLICE - 1) / NSLICE;

    const size_t w16_b   = align256((size_t)V * Dc * sizeof(__half));            // 12.8 MB
    const size_t lam_b   = align256((size_t)V * sizeof(float));                  // 200 KB
    const size_t cidx_b  = align256((size_t)Bn * Lc * sizeof(unsigned short));   // 2 MB
    const size_t offs_b  = align256((size_t)Bn * NSLICE * sizeof(unsigned short));
    const size_t slam_b  = align256((size_t)Bn * sizeof(float));
    const size_t cnt_b   = align256((size_t)Bn * sizeof(int));
    const size_t pnum_b  = align256((size_t)Bn * NSLICE * 32 * sizeof(uint2));   // 8.4 MB
    const size_t need    = w16_b + lam_b + cidx_b + offs_b + slam_b + cnt_b + pnum_b;

    if (ws_size >= need) {
        char* p = (char*)d_ws;
        __half*         w16     = (__half*)p;          p += w16_b;
        float*          lam     = (float*)p;           p += lam_b;
        unsigned short* cidx    = (unsigned short*)p;  p += cidx_b;
        unsigned short* offs    = (unsigned short*)p;  p += offs_b;
        float*          slamArr = (float*)p;           p += slam_b;
        int*            cntArr  = (int*)p;             p += cnt_b;
        uint2*          pnum    = (uint2*)p;
        prep_kernel<<<(V + 3) / 4, 256, 0, stream>>>(emb, w16, lam, V);
        bucket_kernel<<<(Bn + 3) / 4, 256, 0, stream>>>(padded, lam, cidx, offs,
                                                        slamArr, cntArr, Bn, V4);
        const int nblocks = NSLICE * ((Bn + 7) / 8);
        partial_kernel<<<nblocks, 256, 0, stream>>>(cidx, offs, cntArr, w16, pnum, Bn);
        final_kernel<<<(Bn + 3) / 4, 256, 0, stream>>>(pnum, slamArr, cntArr, out, Bn);
    } else if (ws_size >= w16_b + lam_b) {
        __half* w16 = (__half*)d_ws;
        float*  lam = (float*)((char*)d_ws + w16_b);
        prep_kernel<<<(V + 3) / 4, 256, 0, stream>>>(emb, w16, lam, V);
        hyper_enc_kernel<<<Bn, 256, 0, stream>>>(padded, w16, lam, out);
    }
}

// Round 9
// 56.679 us; speedup vs baseline: 2.3616x; 1.0043x over previous
//
#include <hip/hip_runtime.h>
#include <hip/hip_fp16.h>
#include <math.h>

constexpr int PAD = 0;
constexpr int Lc = 128;   // sequence length
constexpr int Dc = 128;   // embedding dim
constexpr int NSLICE = 4; // vocab slices (XCD k owns slice k%4 under round-robin)
constexpr float MIN_NORM = 1e-15f;
constexpr float CLAMP_ABS_EPS = 1e-10f;
constexpr float ATANH_EPS = 1e-7f;

__device__ __forceinline__ float red64(float v) {
    v += __shfl_xor(v, 32);
    v += __shfl_xor(v, 16);
    v += __shfl_xor(v, 8);
    v += __shfl_xor(v, 4);
    v += __shfl_xor(v, 2);
    v += __shfl_xor(v, 1);
    return v;
}

// ---- pass 1: lam[v] and w16[v] = fp16(lam[v] * z[v]) (lam folded into table) ----
__global__ __launch_bounds__(256) void prep_kernel(
        const float* __restrict__ emb,
        __half* __restrict__ w16,
        float* __restrict__ lam, int V) {
    const int row  = blockIdx.x * 4 + (threadIdx.x >> 6);
    const int lane = threadIdx.x & 63;
    if (row >= V) return;
    const float2 z = *reinterpret_cast<const float2*>(emb + (size_t)row * Dc + lane * 2);
    const float p = red64(z.x * z.x + z.y * z.y);
    const float lamv = 2.0f / fmaxf(1.0f - p, MIN_NORM);
    if (lane == 0) lam[row] = lamv;
    *reinterpret_cast<__half2*>(w16 + (size_t)row * Dc + lane * 2) =
        __floats2half2_rn(lamv * z.x, lamv * z.y);
}

// ---- pass 2: per-row bucket: slice-sorted compact token lists + row meta ----
__global__ __launch_bounds__(256) void bucket_kernel(
        const int* __restrict__ padded,
        const float* __restrict__ lam,
        unsigned short* __restrict__ cidx,   // [Bn][128] slice-sorted token ids
        unsigned short* __restrict__ offs,   // [Bn][4] slice start offsets
        float* __restrict__ slamArr,         // [Bn]
        int* __restrict__ cntArr,            // [Bn]
        int Bn, int V4) {
    const int row  = blockIdx.x * 4 + (threadIdx.x >> 6);
    const int lane = threadIdx.x & 63;
    if (row >= Bn) return;

    const int i0 = padded[(size_t)row * Lc + lane];
    const int i1 = padded[(size_t)row * Lc + 64 + lane];
    const bool p0 = (i0 != PAD);
    const bool p1 = (i1 != PAD);
    const float la0 = p0 ? lam[i0] : 0.f;
    const float la1 = p1 ? lam[i1] : 0.f;
    const float slam = red64(la0 + la1);
    // exact slice via compares (float-reciprocal is unsafe at boundaries)
    const int s0 = (i0 >= V4) + (i0 >= 2 * V4) + (i0 >= 3 * V4);
    const int s1 = (i1 >= V4) + (i1 >= 2 * V4) + (i1 >= 3 * V4);
    const unsigned long long lmask = (1ull << lane) - 1ull;

    int running = 0;
    #pragma unroll
    for (int s = 0; s < NSLICE; ++s) {
        const unsigned long long m0 = __ballot(p0 && (s0 == s));
        const unsigned long long m1 = __ballot(p1 && (s1 == s));
        const int c0 = __popcll(m0);
        if (lane == 0) offs[(size_t)row * NSLICE + s] = (unsigned short)running;
        if (p0 && (s0 == s))
            cidx[(size_t)row * Lc + running + __popcll(m0 & lmask)] = (unsigned short)i0;
        if (p1 && (s1 == s))
            cidx[(size_t)row * Lc + running + c0 + __popcll(m1 & lmask)] = (unsigned short)i1;
        running += c0 + __popcll(m1);
    }
    if (lane == 0) { slamArr[row] = slam; cntArr[row] = running; }
}

// ---- pass 3: slice-local gather-add (lean hot loop, fp16 pk adds) ----
__global__ __launch_bounds__(256) void partial_kernel(
        const unsigned short* __restrict__ cidx,
        const unsigned short* __restrict__ offs,
        const int* __restrict__ cntArr,
        const __half* __restrict__ w16,
        uint2* __restrict__ pnum,      // [Bn*4][32] packed half2x2 (128 dims)
        int Bn) {
    const int sl   = blockIdx.x & (NSLICE - 1);   // round-robin -> same XCD per slice
    const int r0   = (blockIdx.x >> 2) * 8;
    const int tid  = threadIdx.x;
    const int w    = tid >> 6;
    const int lane = tid & 63;
    const int half = lane >> 5;
    const int l32  = lane & 31;

    __shared__ int sidx[4][2][Lc];

    #pragma unroll
    for (int rr = 0; rr < 2; ++rr) {
        const int row = r0 + w * 2 + rr;
        if (row >= Bn) continue;
        const int off = offs[(size_t)row * NSLICE + sl];
        const int nxt = (sl < NSLICE - 1) ? (int)offs[(size_t)row * NSLICE + sl + 1]
                                          : cntArr[row];
        const int cnt = nxt - off;
        if (lane < cnt)
            sidx[w][rr][lane] = (int)cidx[(size_t)row * Lc + off + lane];
        if (cnt > 64 && lane < cnt - 64)
            sidx[w][rr][64 + lane] = (int)cidx[(size_t)row * Lc + off + 64 + lane];

        __half2 a0 = __floats2half2_rn(0.f, 0.f);
        __half2 a1 = a0;
        for (int k = half; k < cnt; k += 2) {
            const int idx = sidx[w][rr][k];
            const uint2 r = *reinterpret_cast<const uint2*>(
                w16 + ((size_t)idx << 7) + (l32 << 2));
            a0 = __hadd2(a0, *reinterpret_cast<const __half2*>(&r.x));
            a1 = __hadd2(a1, *reinterpret_cast<const __half2*>(&r.y));
        }
        // combine the two 32-lane halves (different tokens, same dims)
        unsigned u0 = *reinterpret_cast<unsigned*>(&a0);
        unsigned u1 = *reinterpret_cast<unsigned*>(&a1);
        const unsigned o0 = __shfl_xor(u0, 32);
        const unsigned o1 = __shfl_xor(u1, 32);
        a0 = __hadd2(a0, *reinterpret_cast<const __half2*>(&o0));
        a1 = __hadd2(a1, *reinterpret_cast<const __half2*>(&o1));
        if (lane < 32) {
            uint2 u;
            u.x = *reinterpret_cast<unsigned*>(&a0);
            u.y = *reinterpret_cast<unsigned*>(&a1);
            pnum[((size_t)row * NSLICE + sl) * 32 + l32] = u;
        }
    }
}

// ---- pass 4: sum 4 partials per row, norm chain, write 4 replicated chunks ----
__global__ __launch_bounds__(256) void final_kernel(
        const uint2* __restrict__ pnum,
        const float* __restrict__ slamArr,
        const int* __restrict__ cntArr,
        float* __restrict__ out, int Bn) {
    const int row  = blockIdx.x * 4 + (threadIdx.x >> 6);
    const int lane = threadIdx.x & 63;
    const int h    = lane >> 5;
    const int p    = lane & 31;
    if (row >= Bn) return;

    const int   cnt  = cntArr[row];
    float* orow = out + (size_t)row * (4 * Dc);
    if (cnt == 0) {
        if (lane < 32) {
            const float4 z4 = make_float4(0.f, 0.f, 0.f, 0.f);
            #pragma unroll
            for (int sc = 0; sc < 4; ++sc)
                *reinterpret_cast<float4*>(orow + sc * Dc + 4 * p) = z4;
        }
        return;
    }

    float4 v = make_float4(0.f, 0.f, 0.f, 0.f);
    #pragma unroll
    for (int j = 0; j < 2; ++j) {
        const int s = h * 2 + j;
        const uint2 u = pnum[((size_t)row * NSLICE + s) * 32 + p];
        const float2 f0 = __half22float2(*reinterpret_cast<const __half2*>(&u.x));
        const float2 f1 = __half22float2(*reinterpret_cast<const __half2*>(&u.y));
        v.x += f0.x; v.y += f0.y; v.z += f1.x; v.w += f1.y;
    }
    v.x += __shfl_xor(v.x, 32);
    v.y += __shfl_xor(v.y, 32);
    v.z += __shfl_xor(v.z, 32);
    v.w += __shfl_xor(v.w, 32);

    const float cntf = (float)cnt;
    const float rc    = 1.0f / cntf;
    const float dn    = (slamArr[row] - cntf) * rc;             // mean(lam-1)
    const float denom = ((dn >= 0.f) ? 1.0f : -1.0f) * fmaxf(fabsf(dn), CLAMP_ABS_EPS);
    const float s1    = rc / denom;
    const float4 tm = make_float4(v.x * s1, v.y * s1, v.z * s1, v.w * s1);

    const float p2 = (lane < 32) ? (tm.x*tm.x + tm.y*tm.y + tm.z*tm.z + tm.w*tm.w) : 0.f;
    const float n2 = fmaxf(sqrtf(red64(p2)), MIN_NORM);
    const float xc = fminf(n2, 1.0f - ATANH_EPS);
    const float th = xc / (1.0f + sqrtf(fmaxf(1.0f - xc * xc, 0.f)));  // tanh(0.5*artanh)
    const float k1 = th / n2;
    const float4 mid = make_float4(tm.x * k1, tm.y * k1, tm.z * k1, tm.w * k1);

    const float q2 = (lane < 32) ? (mid.x*mid.x + mid.y*mid.y + mid.z*mid.z + mid.w*mid.w) : 0.f;
    const float nm  = fmaxf(sqrtf(red64(q2)), MIN_NORM);
    const float xc2 = fminf(nm, 1.0f - ATANH_EPS);
    const float f   = 0.5f * logf((1.0f + xc2) / (1.0f - xc2));        // artanh
    const float k2  = f / nm;

    if (lane < 32) {
        const float4 o = make_float4(mid.x * k2, mid.y * k2, mid.z * k2, mid.w * k2);
        #pragma unroll
        for (int sc = 0; sc < 4; ++sc)
            *reinterpret_cast<float4*>(orow + sc * Dc + 4 * p) = o;
    }
}

// ---- fallback (small ws): single-kernel gather over w16 table ----
__global__ __launch_bounds__(256) void hyper_enc_kernel(
        const int* __restrict__ padded,
        const __half* __restrict__ w16,
        const float* __restrict__ lam,
        float* __restrict__ out) {
    const int b    = blockIdx.x;
    const int tid  = threadIdx.x;
    const int wave = tid >> 6;
    const int lane = tid & 63;
    const int half = lane >> 5;
    const int l32  = lane & 31;

    __shared__ int   sidx[Lc];
    __shared__ float s_num[8][Dc];
    __shared__ int   s_cnt;
    __shared__ float s_den[2];
    __shared__ float s_red[4];

    int   myidx = 0;
    float mylam = 0.f;
    if (tid < Lc) {
        myidx = padded[(size_t)b * Lc + tid];
        sidx[tid] = myidx;
        mylam = (myidx != PAD) ? lam[myidx] : 0.0f;
    }
    if (tid == 0) s_cnt = 0;
    __syncthreads();
    if (tid < Lc) {
        unsigned long long bal = __ballot(myidx != PAD);
        if (lane == 0) atomicAdd(&s_cnt, (int)__popcll(bal));
        float sl = red64(mylam);
        if (lane == 0) s_den[wave] = sl;
    }

    float4 snum = make_float4(0.f, 0.f, 0.f, 0.f);
    const int lbase = wave * 32 + half;
    __syncthreads();
    #pragma unroll
    for (int j = 0; j < 16; ++j) {
        const int idx = sidx[lbase + 2 * j];
        const uint2 r = *reinterpret_cast<const uint2*>(
            w16 + ((size_t)idx << 7) + (l32 << 2));
        const float2 f0 = __half22float2(*reinterpret_cast<const __half2*>(&r.x));
        const float2 f1 = __half22float2(*reinterpret_cast<const __half2*>(&r.y));
        snum.x += f0.x; snum.y += f0.y; snum.z += f1.x; snum.w += f1.y;
    }
    const int g = wave * 2 + half;
    *reinterpret_cast<float4*>(&s_num[g][l32 * 4]) = snum;
    __syncthreads();

    const int cnt = s_cnt;
    if (cnt == 0) {
        for (int i = tid; i < 4 * Dc; i += 256)
            out[(size_t)b * (4 * Dc) + i] = 0.f;
        return;
    }
    const float Sd = (s_den[0] + s_den[1]) - (float)cnt;

    float nom = 0.f;
    if (tid < Dc) {
        #pragma unroll
        for (int gg = 0; gg < 8; ++gg) nom += s_num[gg][tid];
    }
    float tm = 0.f;
    if (tid < Dc) {
        const float rc    = 1.0f / (float)cnt;
        const float dn    = Sd * rc;
        const float denom = ((dn >= 0.f) ? 1.0f : -1.0f) * fmaxf(fabsf(dn), CLAMP_ABS_EPS);
        tm = (nom * rc) / denom;
    }
    float p2 = red64(tm * tm);
    if (lane == 0) s_red[wave] = p2;
    __syncthreads();
    const float n2 = fmaxf(sqrtf(s_red[0] + s_red[1]), MIN_NORM);
    const float xc = fminf(n2, 1.0f - ATANH_EPS);
    const float t_half = xc / (1.0f + sqrtf(fmaxf(1.0f - xc * xc, 0.f)));
    const float mid = tm * (t_half / n2);
    __syncthreads();
    float q2 = red64(mid * mid);
    if (lane == 0) s_red[wave] = q2;
    __syncthreads();
    const float nm  = fmaxf(sqrtf(s_red[0] + s_red[1]), MIN_NORM);
    const float xc2 = fminf(nm, 1.0f - ATANH_EPS);
    const float f   = 0.5f * logf((1.0f + xc2) / (1.0f - xc2));
    if (tid < Dc) {
        const float o = mid * (f / nm);
        float* orow = out + (size_t)b * (4 * Dc);
        orow[0 * Dc + tid] = o;
        orow[1 * Dc + tid] = o;
        orow[2 * Dc + tid] = o;
        orow[3 * Dc + tid] = o;
    }
}

static inline size_t align256(size_t x) { return (x + 255) & ~(size_t)255; }

extern "C" void kernel_launch(void* const* d_in, const int* in_sizes, int n_in,
                              void* d_out, int out_size, void* d_ws, size_t ws_size,
                              hipStream_t stream) {
    const int*   padded = (const int*)d_in[0];
    const float* emb    = (const float*)d_in[1];
    float*       out    = (float*)d_out;
    const int Bn = in_sizes[0] / Lc;             // 8192
    const int V  = in_sizes[1] / Dc;             // 50000
    const int V4 = (V + NSLICE - 1) / NSLICE;

    const size_t w16_b   = align256((size_t)V * Dc * sizeof(__half));            // 12.8 MB
    const size_t lam_b   = align256((size_t)V * sizeof(float));                  // 200 KB
    const size_t cidx_b  = align256((size_t)Bn * Lc * sizeof(unsigned short));   // 2 MB
    const size_t offs_b  = align256((size_t)Bn * NSLICE * sizeof(unsigned short));
    const size_t slam_b  = align256((size_t)Bn * sizeof(float));
    const size_t cnt_b   = align256((size_t)Bn * sizeof(int));
    const size_t pnum_b  = align256((size_t)Bn * NSLICE * 32 * sizeof(uint2));   // 8.4 MB
    const size_t need    = w16_b + lam_b + cidx_b + offs_b + slam_b + cnt_b + pnum_b;

    if (ws_size >= need) {
        char* p = (char*)d_ws;
        __half*         w16     = (__half*)p;          p += w16_b;
        float*          lam     = (float*)p;           p += lam_b;
        unsigned short* cidx    = (unsigned short*)p;  p += cidx_b;
        unsigned short* offs    = (unsigned short*)p;  p += offs_b;
        float*          slamArr = (float*)p;           p += slam_b;
        int*            cntArr  = (int*)p;             p += cnt_b;
        uint2*          pnum    = (uint2*)p;
        prep_kernel<<<(V + 3) / 4, 256, 0, stream>>>(emb, w16, lam, V);
        bucket_kernel<<<(Bn + 3) / 4, 256, 0, stream>>>(padded, lam, cidx, offs,
                                                        slamArr, cntArr, Bn, V4);
        const int nblocks = NSLICE * ((Bn + 7) / 8);
        partial_kernel<<<nblocks, 256, 0, stream>>>(cidx, offs, cntArr, w16, pnum, Bn);
        final_kernel<<<(Bn + 3) / 4, 256, 0, stream>>>(pnum, slamArr, cntArr, out, Bn);
    } else if (ws_size >= w16_b + lam_b) {
        __half* w16 = (__half*)d_ws;
        float*  lam = (float*)((char*)d_ws + w16_b);
        prep_kernel<<<(V + 3) / 4, 256, 0, stream>>>(emb, w16, lam, V);
        hyper_enc_kernel<<<Bn, 256, 0, stream>>>(padded, w16, lam, out);
    }
}

// Round 10
// 46.079 us; speedup vs baseline: 2.9048x; 1.2300x over previous
//
#include <hip/hip_runtime.h>
#include <hip/hip_fp16.h>
#include <math.h>

constexpr int PAD = 0;
constexpr int Lc = 128;   // sequence length
constexpr int Dc = 128;   // embedding dim
constexpr int NSLICE = 4; // vocab slices (XCD k caches slice k%4 under round-robin)
constexpr float MIN_NORM = 1e-15f;
constexpr float CLAMP_ABS_EPS = 1e-10f;
constexpr float ATANH_EPS = 1e-7f;

__device__ __forceinline__ float red64(float v) {
    v += __shfl_xor(v, 32);
    v += __shfl_xor(v, 16);
    v += __shfl_xor(v, 8);
    v += __shfl_xor(v, 4);
    v += __shfl_xor(v, 2);
    v += __shfl_xor(v, 1);
    return v;
}

__device__ __forceinline__ __half2 h2xadd(__half2 a, int m) {
    unsigned u = *reinterpret_cast<unsigned*>(&a);
    unsigned t = __shfl_xor(u, m);
    return __hadd2(a, *reinterpret_cast<__half2*>(&t));
}

// ---- pass 1: lam[v] and w16[v] = fp16(lam[v] * z[v]) (lam folded into table) ----
__global__ __launch_bounds__(256) void prep_kernel(
        const float* __restrict__ emb,
        __half* __restrict__ w16,
        float* __restrict__ lam, int V) {
    const int row  = blockIdx.x * 4 + (threadIdx.x >> 6);
    const int lane = threadIdx.x & 63;
    if (row >= V) return;
    const float2 z = *reinterpret_cast<const float2*>(emb + (size_t)row * Dc + lane * 2);
    const float p = red64(z.x * z.x + z.y * z.y);
    const float lamv = 2.0f / fmaxf(1.0f - p, MIN_NORM);
    if (lane == 0) lam[row] = lamv;
    *reinterpret_cast<__half2*>(w16 + (size_t)row * Dc + lane * 2) =
        __floats2half2_rn(lamv * z.x, lamv * z.y);
}

// ---- pass 2: per-row bucket: slice-sorted compact token lists + row meta ----
__global__ __launch_bounds__(256) void bucket_kernel(
        const int* __restrict__ padded,
        const float* __restrict__ lam,
        unsigned short* __restrict__ cidx,   // [Bn][128] slice-sorted token ids
        unsigned short* __restrict__ offs,   // [Bn][4] slice start offsets
        float* __restrict__ slamArr,         // [Bn]
        int* __restrict__ cntArr,            // [Bn]
        int Bn, int V4) {
    const int row  = blockIdx.x * 4 + (threadIdx.x >> 6);
    const int lane = threadIdx.x & 63;
    if (row >= Bn) return;

    const int i0 = padded[(size_t)row * Lc + lane];
    const int i1 = padded[(size_t)row * Lc + 64 + lane];
    const bool p0 = (i0 != PAD);
    const bool p1 = (i1 != PAD);
    const float la0 = p0 ? lam[i0] : 0.f;
    const float la1 = p1 ? lam[i1] : 0.f;
    const float slam = red64(la0 + la1);
    const int s0 = (i0 >= V4) + (i0 >= 2 * V4) + (i0 >= 3 * V4);
    const int s1 = (i1 >= V4) + (i1 >= 2 * V4) + (i1 >= 3 * V4);
    const unsigned long long lmask = (1ull << lane) - 1ull;

    int running = 0;
    #pragma unroll
    for (int s = 0; s < NSLICE; ++s) {
        const unsigned long long m0 = __ballot(p0 && (s0 == s));
        const unsigned long long m1 = __ballot(p1 && (s1 == s));
        const int c0 = __popcll(m0);
        if (lane == 0) offs[(size_t)row * NSLICE + s] = (unsigned short)running;
        if (p0 && (s0 == s))
            cidx[(size_t)row * Lc + running + __popcll(m0 & lmask)] = (unsigned short)i0;
        if (p1 && (s1 == s))
            cidx[(size_t)row * Lc + running + c0 + __popcll(m1 & lmask)] = (unsigned short)i1;
        running += c0 + __popcll(m1);
    }
    if (lane == 0) { slamArr[row] = slam; cntArr[row] = running; }
}

// ---- pass 3: slice-local gather-add. 4 lanes-quarters = 4 tokens in flight,
//      16B loads (one full fp16 row per 16 lanes), 2x manual unroll -> 8 deep ----
__global__ __launch_bounds__(256) void partial_kernel(
        const unsigned short* __restrict__ cidx,
        const unsigned short* __restrict__ offs,
        const int* __restrict__ cntArr,
        const __half* __restrict__ w16,
        uint2* __restrict__ pnum,      // [Bn*4][32] packed half2x2 (128 dims)
        int Bn) {
    const int sl   = blockIdx.x & (NSLICE - 1);   // round-robin -> stable XCD per slice
    const int r0   = (blockIdx.x >> 2) * 8;
    const int tid  = threadIdx.x;
    const int w    = tid >> 6;
    const int lane = tid & 63;
    const int q    = lane >> 4;    // token phase within wave
    const int l16  = lane & 15;    // 16B chunk within the 256B row

    __shared__ int sidx[4][2][Lc];

    #pragma unroll
    for (int rr = 0; rr < 2; ++rr) {
        const int row = r0 + w * 2 + rr;
        if (row >= Bn) continue;
        const int off = offs[(size_t)row * NSLICE + sl];
        const int nxt = (sl < NSLICE - 1) ? (int)offs[(size_t)row * NSLICE + sl + 1]
                                          : cntArr[row];
        const int cnt = nxt - off;
        if (lane < cnt)
            sidx[w][rr][lane] = (int)cidx[(size_t)row * Lc + off + lane];
        if (64 + lane < cnt)
            sidx[w][rr][64 + lane] = (int)cidx[(size_t)row * Lc + off + 64 + lane];

        const __half2 hz = __floats2half2_rn(0.f, 0.f);
        __half2 a0 = hz, a1 = hz, a2 = hz, a3 = hz;
        for (int k = q; k < cnt; k += 8) {
            const bool okb = (k + 4) < cnt;
            const int  kb  = okb ? (k + 4) : (cnt - 1);     // clamped, always valid
            const int  ia  = sidx[w][rr][k];
            const int  ib  = sidx[w][rr][kb];
            const uint4 va = *reinterpret_cast<const uint4*>(
                w16 + ((size_t)ia << 7) + (l16 << 3));
            const uint4 vb = *reinterpret_cast<const uint4*>(
                w16 + ((size_t)ib << 7) + (l16 << 3));
            a0 = __hadd2(a0, *reinterpret_cast<const __half2*>(&va.x));
            a1 = __hadd2(a1, *reinterpret_cast<const __half2*>(&va.y));
            a2 = __hadd2(a2, *reinterpret_cast<const __half2*>(&va.z));
            a3 = __hadd2(a3, *reinterpret_cast<const __half2*>(&va.w));
            const __half2 b0 = okb ? *reinterpret_cast<const __half2*>(&vb.x) : hz;
            const __half2 b1 = okb ? *reinterpret_cast<const __half2*>(&vb.y) : hz;
            const __half2 b2 = okb ? *reinterpret_cast<const __half2*>(&vb.z) : hz;
            const __half2 b3 = okb ? *reinterpret_cast<const __half2*>(&vb.w) : hz;
            a0 = __hadd2(a0, b0);
            a1 = __hadd2(a1, b1);
            a2 = __hadd2(a2, b2);
            a3 = __hadd2(a3, b3);
        }
        // combine the 4 quarters (same dims, different tokens)
        a0 = h2xadd(a0, 16); a1 = h2xadd(a1, 16); a2 = h2xadd(a2, 16); a3 = h2xadd(a3, 16);
        a0 = h2xadd(a0, 32); a1 = h2xadd(a1, 32); a2 = h2xadd(a2, 32); a3 = h2xadd(a3, 32);
        if (lane < 16) {
            uint4 u;
            u.x = *reinterpret_cast<unsigned*>(&a0);
            u.y = *reinterpret_cast<unsigned*>(&a1);
            u.z = *reinterpret_cast<unsigned*>(&a2);
            u.w = *reinterpret_cast<unsigned*>(&a3);
            *reinterpret_cast<uint4*>(
                &pnum[((size_t)row * NSLICE + sl) * 32 + (l16 << 1)]) = u;
        }
    }
}

// ---- pass 4: sum 4 partials per row, norm chain, write 4 replicated chunks ----
__global__ __launch_bounds__(256) void final_kernel(
        const uint2* __restrict__ pnum,
        const float* __restrict__ slamArr,
        const int* __restrict__ cntArr,
        float* __restrict__ out, int Bn) {
    const int row  = blockIdx.x * 4 + (threadIdx.x >> 6);
    const int lane = threadIdx.x & 63;
    const int h    = lane >> 5;
    const int p    = lane & 31;
    if (row >= Bn) return;

    const int cnt = cntArr[row];
    float* orow = out + (size_t)row * (4 * Dc);
    if (cnt == 0) {
        if (lane < 32) {
            const float4 z4 = make_float4(0.f, 0.f, 0.f, 0.f);
            #pragma unroll
            for (int sc = 0; sc < 4; ++sc)
                *reinterpret_cast<float4*>(orow + sc * Dc + 4 * p) = z4;
        }
        return;
    }

    float4 v = make_float4(0.f, 0.f, 0.f, 0.f);
    #pragma unroll
    for (int j = 0; j < 2; ++j) {
        const int s = h * 2 + j;
        const uint2 u = pnum[((size_t)row * NSLICE + s) * 32 + p];
        const float2 f0 = __half22float2(*reinterpret_cast<const __half2*>(&u.x));
        const float2 f1 = __half22float2(*reinterpret_cast<const __half2*>(&u.y));
        v.x += f0.x; v.y += f0.y; v.z += f1.x; v.w += f1.y;
    }
    v.x += __shfl_xor(v.x, 32);
    v.y += __shfl_xor(v.y, 32);
    v.z += __shfl_xor(v.z, 32);
    v.w += __shfl_xor(v.w, 32);

    const float cntf  = (float)cnt;
    const float rc    = 1.0f / cntf;
    const float dn    = (slamArr[row] - cntf) * rc;             // mean(lam-1)
    const float denom = ((dn >= 0.f) ? 1.0f : -1.0f) * fmaxf(fabsf(dn), CLAMP_ABS_EPS);
    const float s1    = rc / denom;
    const float4 tm = make_float4(v.x * s1, v.y * s1, v.z * s1, v.w * s1);

    const float p2 = (lane < 32) ? (tm.x*tm.x + tm.y*tm.y + tm.z*tm.z + tm.w*tm.w) : 0.f;
    const float n2 = fmaxf(sqrtf(red64(p2)), MIN_NORM);
    const float xc = fminf(n2, 1.0f - ATANH_EPS);
    const float th = xc / (1.0f + sqrtf(fmaxf(1.0f - xc * xc, 0.f)));  // tanh(0.5*artanh)
    const float k1 = th / n2;
    const float4 mid = make_float4(tm.x * k1, tm.y * k1, tm.z * k1, tm.w * k1);

    const float q2 = (lane < 32) ? (mid.x*mid.x + mid.y*mid.y + mid.z*mid.z + mid.w*mid.w) : 0.f;
    const float nm  = fmaxf(sqrtf(red64(q2)), MIN_NORM);
    const float xc2 = fminf(nm, 1.0f - ATANH_EPS);
    const float f   = 0.5f * logf((1.0f + xc2) / (1.0f - xc2));        // artanh
    const float k2  = f / nm;

    if (lane < 32) {
        const float4 o = make_float4(mid.x * k2, mid.y * k2, mid.z * k2, mid.w * k2);
        #pragma unroll
        for (int sc = 0; sc < 4; ++sc)
            *reinterpret_cast<float4*>(orow + sc * Dc + 4 * p) = o;
    }
}

// ---- fallback (small ws): single-kernel gather over w16 table ----
__global__ __launch_bounds__(256) void hyper_enc_kernel(
        const int* __restrict__ padded,
        const __half* __restrict__ w16,
        const float* __restrict__ lam,
        float* __restrict__ out) {
    const int b    = blockIdx.x;
    const int tid  = threadIdx.x;
    const int wave = tid >> 6;
    const int lane = tid & 63;
    const int half = lane >> 5;
    const int l32  = lane & 31;

    __shared__ int   sidx[Lc];
    __shared__ float s_num[8][Dc];
    __shared__ int   s_cnt;
    __shared__ float s_den[2];
    __shared__ float s_red[4];

    int   myidx = 0;
    float mylam = 0.f;
    if (tid < Lc) {
        myidx = padded[(size_t)b * Lc + tid];
        sidx[tid] = myidx;
        mylam = (myidx != PAD) ? lam[myidx] : 0.0f;
    }
    if (tid == 0) s_cnt = 0;
    __syncthreads();
    if (tid < Lc) {
        unsigned long long bal = __ballot(myidx != PAD);
        if (lane == 0) atomicAdd(&s_cnt, (int)__popcll(bal));
        float sl = red64(mylam);
        if (lane == 0) s_den[wave] = sl;
    }

    float4 snum = make_float4(0.f, 0.f, 0.f, 0.f);
    const int lbase = wave * 32 + half;
    __syncthreads();
    #pragma unroll
    for (int j = 0; j < 16; ++j) {
        const int idx = sidx[lbase + 2 * j];
        const uint2 r = *reinterpret_cast<const uint2*>(
            w16 + ((size_t)idx << 7) + (l32 << 2));
        const float2 f0 = __half22float2(*reinterpret_cast<const __half2*>(&r.x));
        const float2 f1 = __half22float2(*reinterpret_cast<const __half2*>(&r.y));
        snum.x += f0.x; snum.y += f0.y; snum.z += f1.x; snum.w += f1.y;
    }
    const int g = wave * 2 + half;
    *reinterpret_cast<float4*>(&s_num[g][l32 * 4]) = snum;
    __syncthreads();

    const int cnt = s_cnt;
    if (cnt == 0) {
        for (int i = tid; i < 4 * Dc; i += 256)
            out[(size_t)b * (4 * Dc) + i] = 0.f;
        return;
    }
    const float Sd = (s_den[0] + s_den[1]) - (float)cnt;

    float nom = 0.f;
    if (tid < Dc) {
        #pragma unroll
        for (int gg = 0; gg < 8; ++gg) nom += s_num[gg][tid];
    }
    float tm = 0.f;
    if (tid < Dc) {
        const float rc    = 1.0f / (float)cnt;
        const float dn    = Sd * rc;
        const float denom = ((dn >= 0.f) ? 1.0f : -1.0f) * fmaxf(fabsf(dn), CLAMP_ABS_EPS);
        tm = (nom * rc) / denom;
    }
    float p2 = red64(tm * tm);
    if (lane == 0) s_red[wave] = p2;
    __syncthreads();
    const float n2 = fmaxf(sqrtf(s_red[0] + s_red[1]), MIN_NORM);
    const float xc = fminf(n2, 1.0f - ATANH_EPS);
    const float t_half = xc / (1.0f + sqrtf(fmaxf(1.0f - xc * xc, 0.f)));
    const float mid = tm * (t_half / n2);
    __syncthreads();
    float q2 = red64(mid * mid);
    if (lane == 0) s_red[wave] = q2;
    __syncthreads();
    const float nm  = fmaxf(sqrtf(s_red[0] + s_red[1]), MIN_NORM);
    const float xc2 = fminf(nm, 1.0f - ATANH_EPS);
    const float f   = 0.5f * logf((1.0f + xc2) / (1.0f - xc2));
    if (tid < Dc) {
        const float o = mid * (f / nm);
        float* orow = out + (size_t)b * (4 * Dc);
        orow[0 * Dc + tid] = o;
        orow[1 * Dc + tid] = o;
        orow[2 * Dc + tid] = o;
        orow[3 * Dc + tid] = o;
    }
}

static inline size_t align256(size_t x) { return (x + 255) & ~(size_t)255; }

extern "C" void kernel_launch(void* const* d_in, const int* in_sizes, int n_in,
                              void* d_out, int out_size, void* d_ws, size_t ws_size,
                              hipStream_t stream) {
    const int*   padded = (const int*)d_in[0];
    const float* emb    = (const float*)d_in[1];
    float*       out    = (float*)d_out;
    const int Bn = in_sizes[0] / Lc;             // 8192
    const int V  = in_sizes[1] / Dc;             // 50000
    const int V4 = (V + NSLICE - 1) / NSLICE;

    const size_t w16_b   = align256((size_t)V * Dc * sizeof(__half));            // 12.8 MB
    const size_t lam_b   = align256((size_t)V * sizeof(float));                  // 200 KB
    const size_t cidx_b  = align256((size_t)Bn * Lc * sizeof(unsigned short));   // 2 MB
    const size_t offs_b  = align256((size_t)Bn * NSLICE * sizeof(unsigned short));
    const size_t slam_b  = align256((size_t)Bn * sizeof(float));
    const size_t cnt_b   = align256((size_t)Bn * sizeof(int));
    const size_t pnum_b  = align256((size_t)Bn * NSLICE * 32 * sizeof(uint2));   // 8.4 MB
    const size_t need    = w16_b + lam_b + cidx_b + offs_b + slam_b + cnt_b + pnum_b;

    if (ws_size >= need) {
        char* p = (char*)d_ws;
        __half*         w16     = (__half*)p;          p += w16_b;
        float*          lam     = (float*)p;           p += lam_b;
        unsigned short* cidx    = (unsigned short*)p;  p += cidx_b;
        unsigned short* offs    = (unsigned short*)p;  p += offs_b;
        float*          slamArr = (float*)p;           p += slam_b;
        int*            cntArr  = (int*)p;             p += cnt_b;
        uint2*          pnum    = (uint2*)p;
        prep_kernel<<<(V + 3) / 4, 256, 0, stream>>>(emb, w16, lam, V);
        bucket_kernel<<<(Bn + 3) / 4, 256, 0, stream>>>(padded, lam, cidx, offs,
                                                        slamArr, cntArr, Bn, V4);
        const int nblocks = NSLICE * ((Bn + 7) / 8);
        partial_kernel<<<nblocks, 256, 0, stream>>>(cidx, offs, cntArr, w16, pnum, Bn);
        final_kernel<<<(Bn + 3) / 4, 256, 0, stream>>>(pnum, slamArr, cntArr, out, Bn);
    } else if (ws_size >= w16_b + lam_b) {
        __half* w16 = (__half*)d_ws;
        float*  lam = (float*)((char*)d_ws + w16_b);
        prep_kernel<<<(V + 3) / 4, 256, 0, stream>>>(emb, w16, lam, V);
        hyper_enc_kernel<<<Bn, 256, 0, stream>>>(padded, w16, lam, out);
    }
}

// Round 11
// 45.971 us; speedup vs baseline: 2.9116x; 1.0023x over previous
//
#include <hip/hip_runtime.h>
#include <hip/hip_fp16.h>
#include <math.h>

constexpr int PAD = 0;
constexpr int Lc = 128;   // sequence length
constexpr int Dc = 128;   // embedding dim
constexpr int NSLICE = 4; // vocab slices (XCD k caches slice k%4 under round-robin)
constexpr float MIN_NORM = 1e-15f;
constexpr float CLAMP_ABS_EPS = 1e-10f;
constexpr float ATANH_EPS = 1e-7f;

__device__ __forceinline__ float red64(float v) {
    v += __shfl_xor(v, 32);
    v += __shfl_xor(v, 16);
    v += __shfl_xor(v, 8);
    v += __shfl_xor(v, 4);
    v += __shfl_xor(v, 2);
    v += __shfl_xor(v, 1);
    return v;
}

__device__ __forceinline__ __half2 h2xadd(__half2 a, int m) {
    unsigned u = *reinterpret_cast<unsigned*>(&a);
    unsigned t = __shfl_xor(u, m);
    return __hadd2(a, *reinterpret_cast<__half2*>(&t));
}

// ---- pass 1: lam[v], w16[v] = fp16(lam[v]*z[v]); row V is an all-zero dummy ----
__global__ __launch_bounds__(256) void prep_kernel(
        const float* __restrict__ emb,
        __half* __restrict__ w16,
        float* __restrict__ lam, int V) {
    const int row  = blockIdx.x * 4 + (threadIdx.x >> 6);
    const int lane = threadIdx.x & 63;
    if (row > V) return;
    if (row == V) {   // dummy zero row for pad gathers
        *reinterpret_cast<__half2*>(w16 + (size_t)V * Dc + lane * 2) =
            __floats2half2_rn(0.f, 0.f);
        return;
    }
    const float2 z = *reinterpret_cast<const float2*>(emb + (size_t)row * Dc + lane * 2);
    const float p = red64(z.x * z.x + z.y * z.y);
    const float lamv = 2.0f / fmaxf(1.0f - p, MIN_NORM);
    if (lane == 0) lam[row] = lamv;
    *reinterpret_cast<__half2*>(w16 + (size_t)row * Dc + lane * 2) =
        __floats2half2_rn(lamv * z.x, lamv * z.y);
}

// ---- pass 2: per-row bucket: slice-sorted compact token lists + row meta ----
__global__ __launch_bounds__(256) void bucket_kernel(
        const int* __restrict__ padded,
        const float* __restrict__ lam,
        unsigned short* __restrict__ cidx,   // [Bn][128] slice-sorted token ids
        unsigned short* __restrict__ offs,   // [Bn][4] slice start offsets
        float* __restrict__ slamArr,         // [Bn]
        int* __restrict__ cntArr,            // [Bn]
        int Bn, int V4) {
    const int row  = blockIdx.x * 4 + (threadIdx.x >> 6);
    const int lane = threadIdx.x & 63;
    if (row >= Bn) return;

    const int i0 = padded[(size_t)row * Lc + lane];
    const int i1 = padded[(size_t)row * Lc + 64 + lane];
    const bool p0 = (i0 != PAD);
    const bool p1 = (i1 != PAD);
    const float la0 = p0 ? lam[i0] : 0.f;
    const float la1 = p1 ? lam[i1] : 0.f;
    const float slam = red64(la0 + la1);
    const int s0 = (i0 >= V4) + (i0 >= 2 * V4) + (i0 >= 3 * V4);
    const int s1 = (i1 >= V4) + (i1 >= 2 * V4) + (i1 >= 3 * V4);
    const unsigned long long lmask = (1ull << lane) - 1ull;

    int running = 0;
    #pragma unroll
    for (int s = 0; s < NSLICE; ++s) {
        const unsigned long long m0 = __ballot(p0 && (s0 == s));
        const unsigned long long m1 = __ballot(p1 && (s1 == s));
        const int c0 = __popcll(m0);
        if (lane == 0) offs[(size_t)row * NSLICE + s] = (unsigned short)running;
        if (p0 && (s0 == s))
            cidx[(size_t)row * Lc + running + __popcll(m0 & lmask)] = (unsigned short)i0;
        if (p1 && (s1 == s))
            cidx[(size_t)row * Lc + running + c0 + __popcll(m1 & lmask)] = (unsigned short)i1;
        running += c0 + __popcll(m1);
    }
    if (lane == 0) { slamArr[row] = slam; cntArr[row] = running; }
}

// ---- pass 3: slice-local gather-add. 16-lane quarters, 4x unroll ->
//      16 tokens in flight per wave; branch-free via dummy zero row V ----
__global__ __launch_bounds__(256) void partial_kernel(
        const unsigned short* __restrict__ cidx,
        const unsigned short* __restrict__ offs,
        const int* __restrict__ cntArr,
        const __half* __restrict__ w16,
        uint2* __restrict__ pnum,      // [Bn*4][32] packed half2x2 (128 dims)
        int Bn, int V) {
    const int sl   = blockIdx.x & (NSLICE - 1);   // round-robin -> stable XCD per slice
    const int r0   = (blockIdx.x >> 2) * 8;
    const int tid  = threadIdx.x;
    const int w    = tid >> 6;
    const int lane = tid & 63;
    const int q    = lane >> 4;    // token phase within wave
    const int l16  = lane & 15;    // 16B chunk within the 256B row

    __shared__ int sidx[4][2][Lc + 16];

    #pragma unroll
    for (int rr = 0; rr < 2; ++rr) {
        const int row = r0 + w * 2 + rr;
        if (row >= Bn) continue;
        const int off = offs[(size_t)row * NSLICE + sl];
        const int nxt = (sl < NSLICE - 1) ? (int)offs[(size_t)row * NSLICE + sl + 1]
                                          : cntArr[row];
        const int cnt = nxt - off;
        // stage all 128 slots + 16 pad slots; out-of-range -> dummy row V
        {
            const int s0i = off + lane;
            const int s1i = off + 64 + lane;
            const int t0 = (int)cidx[(size_t)row * Lc + (s0i < Lc ? s0i : Lc - 1)];
            const int t1 = (int)cidx[(size_t)row * Lc + (s1i < Lc ? s1i : Lc - 1)];
            sidx[w][rr][lane]      = (lane      < cnt) ? t0 : V;
            sidx[w][rr][64 + lane] = (64 + lane < cnt) ? t1 : V;
            if (lane < 16) sidx[w][rr][Lc + lane] = V;
        }

        const __half2 hz = __floats2half2_rn(0.f, 0.f);
        __half2 a0 = hz, a1 = hz, a2 = hz, a3 = hz;
        __half2 b0 = hz, b1 = hz, b2 = hz, b3 = hz;
        for (int k = q; k < cnt; k += 16) {
            const int i0 = sidx[w][rr][k];
            const int i1 = sidx[w][rr][k + 4];
            const int i2 = sidx[w][rr][k + 8];
            const int i3 = sidx[w][rr][k + 12];
            const uint4 v0 = *reinterpret_cast<const uint4*>(w16 + ((size_t)i0 << 7) + (l16 << 3));
            const uint4 v1 = *reinterpret_cast<const uint4*>(w16 + ((size_t)i1 << 7) + (l16 << 3));
            const uint4 v2 = *reinterpret_cast<const uint4*>(w16 + ((size_t)i2 << 7) + (l16 << 3));
            const uint4 v3 = *reinterpret_cast<const uint4*>(w16 + ((size_t)i3 << 7) + (l16 << 3));
            a0 = __hadd2(a0, *reinterpret_cast<const __half2*>(&v0.x));
            a1 = __hadd2(a1, *reinterpret_cast<const __half2*>(&v0.y));
            a2 = __hadd2(a2, *reinterpret_cast<const __half2*>(&v0.z));
            a3 = __hadd2(a3, *reinterpret_cast<const __half2*>(&v0.w));
            b0 = __hadd2(b0, *reinterpret_cast<const __half2*>(&v1.x));
            b1 = __hadd2(b1, *reinterpret_cast<const __half2*>(&v1.y));
            b2 = __hadd2(b2, *reinterpret_cast<const __half2*>(&v1.z));
            b3 = __hadd2(b3, *reinterpret_cast<const __half2*>(&v1.w));
            a0 = __hadd2(a0, *reinterpret_cast<const __half2*>(&v2.x));
            a1 = __hadd2(a1, *reinterpret_cast<const __half2*>(&v2.y));
            a2 = __hadd2(a2, *reinterpret_cast<const __half2*>(&v2.z));
            a3 = __hadd2(a3, *reinterpret_cast<const __half2*>(&v2.w));
            b0 = __hadd2(b0, *reinterpret_cast<const __half2*>(&v3.x));
            b1 = __hadd2(b1, *reinterpret_cast<const __half2*>(&v3.y));
            b2 = __hadd2(b2, *reinterpret_cast<const __half2*>(&v3.z));
            b3 = __hadd2(b3, *reinterpret_cast<const __half2*>(&v3.w));
        }
        a0 = __hadd2(a0, b0); a1 = __hadd2(a1, b1);
        a2 = __hadd2(a2, b2); a3 = __hadd2(a3, b3);
        // combine the 4 quarters (same dims, different tokens)
        a0 = h2xadd(a0, 16); a1 = h2xadd(a1, 16); a2 = h2xadd(a2, 16); a3 = h2xadd(a3, 16);
        a0 = h2xadd(a0, 32); a1 = h2xadd(a1, 32); a2 = h2xadd(a2, 32); a3 = h2xadd(a3, 32);
        if (lane < 16) {
            uint4 u;
            u.x = *reinterpret_cast<unsigned*>(&a0);
            u.y = *reinterpret_cast<unsigned*>(&a1);
            u.z = *reinterpret_cast<unsigned*>(&a2);
            u.w = *reinterpret_cast<unsigned*>(&a3);
            *reinterpret_cast<uint4*>(
                &pnum[((size_t)row * NSLICE + sl) * 32 + (l16 << 1)]) = u;
        }
    }
}

// ---- pass 4: sum 4 partials per row, norm chain, write 4 replicated chunks ----
__global__ __launch_bounds__(256) void final_kernel(
        const uint2* __restrict__ pnum,
        const float* __restrict__ slamArr,
        const int* __restrict__ cntArr,
        float* __restrict__ out, int Bn) {
    const int row  = blockIdx.x * 4 + (threadIdx.x >> 6);
    const int lane = threadIdx.x & 63;
    const int h    = lane >> 5;
    const int p    = lane & 31;
    if (row >= Bn) return;

    const int cnt = cntArr[row];
    float* orow = out + (size_t)row * (4 * Dc);
    if (cnt == 0) {
        if (lane < 32) {
            const float4 z4 = make_float4(0.f, 0.f, 0.f, 0.f);
            #pragma unroll
            for (int sc = 0; sc < 4; ++sc)
                *reinterpret_cast<float4*>(orow + sc * Dc + 4 * p) = z4;
        }
        return;
    }

    float4 v = make_float4(0.f, 0.f, 0.f, 0.f);
    #pragma unroll
    for (int j = 0; j < 2; ++j) {
        const int s = h * 2 + j;
        const uint2 u = pnum[((size_t)row * NSLICE + s) * 32 + p];
        const float2 f0 = __half22float2(*reinterpret_cast<const __half2*>(&u.x));
        const float2 f1 = __half22float2(*reinterpret_cast<const __half2*>(&u.y));
        v.x += f0.x; v.y += f0.y; v.z += f1.x; v.w += f1.y;
    }
    v.x += __shfl_xor(v.x, 32);
    v.y += __shfl_xor(v.y, 32);
    v.z += __shfl_xor(v.z, 32);
    v.w += __shfl_xor(v.w, 32);

    const float cntf  = (float)cnt;
    const float rc    = 1.0f / cntf;
    const float dn    = (slamArr[row] - cntf) * rc;             // mean(lam-1)
    const float denom = ((dn >= 0.f) ? 1.0f : -1.0f) * fmaxf(fabsf(dn), CLAMP_ABS_EPS);
    const float s1    = rc / denom;
    const float4 tm = make_float4(v.x * s1, v.y * s1, v.z * s1, v.w * s1);

    const float p2 = (lane < 32) ? (tm.x*tm.x + tm.y*tm.y + tm.z*tm.z + tm.w*tm.w) : 0.f;
    const float n2 = fmaxf(sqrtf(red64(p2)), MIN_NORM);
    const float xc = fminf(n2, 1.0f - ATANH_EPS);
    const float th = xc / (1.0f + sqrtf(fmaxf(1.0f - xc * xc, 0.f)));  // tanh(0.5*artanh)
    const float k1 = th / n2;
    const float4 mid = make_float4(tm.x * k1, tm.y * k1, tm.z * k1, tm.w * k1);

    const float q2 = (lane < 32) ? (mid.x*mid.x + mid.y*mid.y + mid.z*mid.z + mid.w*mid.w) : 0.f;
    const float nm  = fmaxf(sqrtf(red64(q2)), MIN_NORM);
    const float xc2 = fminf(nm, 1.0f - ATANH_EPS);
    const float f   = 0.5f * logf((1.0f + xc2) / (1.0f - xc2));        // artanh
    const float k2  = f / nm;

    if (lane < 32) {
        const float4 o = make_float4(mid.x * k2, mid.y * k2, mid.z * k2, mid.w * k2);
        #pragma unroll
        for (int sc = 0; sc < 4; ++sc)
            *reinterpret_cast<float4*>(orow + sc * Dc + 4 * p) = o;
    }
}

// ---- fallback (small ws): single-kernel gather over w16 table ----
__global__ __launch_bounds__(256) void hyper_enc_kernel(
        const int* __restrict__ padded,
        const __half* __restrict__ w16,
        const float* __restrict__ lam,
        float* __restrict__ out) {
    const int b    = blockIdx.x;
    const int tid  = threadIdx.x;
    const int wave = tid >> 6;
    const int lane = tid & 63;
    const int half = lane >> 5;
    const int l32  = lane & 31;

    __shared__ int   sidx[Lc];
    __shared__ float s_num[8][Dc];
    __shared__ int   s_cnt;
    __shared__ float s_den[2];
    __shared__ float s_red[4];

    int   myidx = 0;
    float mylam = 0.f;
    if (tid < Lc) {
        myidx = padded[(size_t)b * Lc + tid];
        sidx[tid] = myidx;
        mylam = (myidx != PAD) ? lam[myidx] : 0.0f;
    }
    if (tid == 0) s_cnt = 0;
    __syncthreads();
    if (tid < Lc) {
        unsigned long long bal = __ballot(myidx != PAD);
        if (lane == 0) atomicAdd(&s_cnt, (int)__popcll(bal));
        float sl = red64(mylam);
        if (lane == 0) s_den[wave] = sl;
    }

    float4 snum = make_float4(0.f, 0.f, 0.f, 0.f);
    const int lbase = wave * 32 + half;
    __syncthreads();
    #pragma unroll
    for (int j = 0; j < 16; ++j) {
        const int idx = sidx[lbase + 2 * j];
        const uint2 r = *reinterpret_cast<const uint2*>(
            w16 + ((size_t)idx << 7) + (l32 << 2));
        const float2 f0 = __half22float2(*reinterpret_cast<const __half2*>(&r.x));
        const float2 f1 = __half22float2(*reinterpret_cast<const __half2*>(&r.y));
        snum.x += f0.x; snum.y += f0.y; snum.z += f1.x; snum.w += f1.y;
    }
    const int g = wave * 2 + half;
    *reinterpret_cast<float4*>(&s_num[g][l32 * 4]) = snum;
    __syncthreads();

    const int cnt = s_cnt;
    if (cnt == 0) {
        for (int i = tid; i < 4 * Dc; i += 256)
            out[(size_t)b * (4 * Dc) + i] = 0.f;
        return;
    }
    const float Sd = (s_den[0] + s_den[1]) - (float)cnt;

    float nom = 0.f;
    if (tid < Dc) {
        #pragma unroll
        for (int gg = 0; gg < 8; ++gg) nom += s_num[gg][tid];
    }
    float tm = 0.f;
    if (tid < Dc) {
        const float rc    = 1.0f / (float)cnt;
        const float dn    = Sd * rc;
        const float denom = ((dn >= 0.f) ? 1.0f : -1.0f) * fmaxf(fabsf(dn), CLAMP_ABS_EPS);
        tm = (nom * rc) / denom;
    }
    float p2 = red64(tm * tm);
    if (lane == 0) s_red[wave] = p2;
    __syncthreads();
    const float n2 = fmaxf(sqrtf(s_red[0] + s_red[1]), MIN_NORM);
    const float xc = fminf(n2, 1.0f - ATANH_EPS);
    const float t_half = xc / (1.0f + sqrtf(fmaxf(1.0f - xc * xc, 0.f)));
    const float mid = tm * (t_half / n2);
    __syncthreads();
    float q2 = red64(mid * mid);
    if (lane == 0) s_red[wave] = q2;
    __syncthreads();
    const float nm  = fmaxf(sqrtf(s_red[0] + s_red[1]), MIN_NORM);
    const float xc2 = fminf(nm, 1.0f - ATANH_EPS);
    const float f   = 0.5f * logf((1.0f + xc2) / (1.0f - xc2));
    if (tid < Dc) {
        const float o = mid * (f / nm);
        float* orow = out + (size_t)b * (4 * Dc);
        orow[0 * Dc + tid] = o;
        orow[1 * Dc + tid] = o;
        orow[2 * Dc + tid] = o;
        orow[3 * Dc + tid] = o;
    }
}

static inline size_t align256(size_t x) { return (x + 255) & ~(size_t)255; }

extern "C" void kernel_launch(void* const* d_in, const int* in_sizes, int n_in,
                              void* d_out, int out_size, void* d_ws, size_t ws_size,
                              hipStream_t stream) {
    const int*   padded = (const int*)d_in[0];
    const float* emb    = (const float*)d_in[1];
    float*       out    = (float*)d_out;
    const int Bn = in_sizes[0] / Lc;             // 8192
    const int V  = in_sizes[1] / Dc;             // 50000
    const int V4 = (V + NSLICE - 1) / NSLICE;

    const size_t w16_b   = align256((size_t)(V + 1) * Dc * sizeof(__half));      // 12.8 MB (+dummy row)
    const size_t lam_b   = align256((size_t)V * sizeof(float));                  // 200 KB
    const size_t cidx_b  = align256((size_t)Bn * Lc * sizeof(unsigned short));   // 2 MB
    const size_t offs_b  = align256((size_t)Bn * NSLICE * sizeof(unsigned short));
    const size_t slam_b  = align256((size_t)Bn * sizeof(float));
    const size_t cnt_b   = align256((size_t)Bn * sizeof(int));
    const size_t pnum_b  = align256((size_t)Bn * NSLICE * 32 * sizeof(uint2));   // 8.4 MB
    const size_t need    = w16_b + lam_b + cidx_b + offs_b + slam_b + cnt_b + pnum_b;

    if (ws_size >= need) {
        char* p = (char*)d_ws;
        __half*         w16     = (__half*)p;          p += w16_b;
        float*          lam     = (float*)p;           p += lam_b;
        unsigned short* cidx    = (unsigned short*)p;  p += cidx_b;
        unsigned short* offs    = (unsigned short*)p;  p += offs_b;
        float*          slamArr = (float*)p;           p += slam_b;
        int*            cntArr  = (int*)p;             p += cnt_b;
        uint2*          pnum    = (uint2*)p;
        prep_kernel<<<(V + 1 + 3) / 4, 256, 0, stream>>>(emb, w16, lam, V);
        bucket_kernel<<<(Bn + 3) / 4, 256, 0, stream>>>(padded, lam, cidx, offs,
                                                        slamArr, cntArr, Bn, V4);
        const int nblocks = NSLICE * ((Bn + 7) / 8);
        partial_kernel<<<nblocks, 256, 0, stream>>>(cidx, offs, cntArr, w16, pnum, Bn, V);
        final_kernel<<<(Bn + 3) / 4, 256, 0, stream>>>(pnum, slamArr, cntArr, out, Bn);
    } else if (ws_size >= w16_b + lam_b) {
        __half* w16 = (__half*)d_ws;
        float*  lam = (float*)((char*)d_ws + w16_b);
        prep_kernel<<<(V + 1 + 3) / 4, 256, 0, stream>>>(emb, w16, lam, V);
        hyper_enc_kernel<<<Bn, 256, 0, stream>>>(padded, w16, lam, out);
    }
}